// Round 11
// baseline (117.491 us; speedup 1.0000x reference)
//
#include <hip/hip_runtime.h>
#include <stdint.h>

typedef __attribute__((ext_vector_type(8))) short bf16x8;
typedef __attribute__((ext_vector_type(4))) float f32x4;
typedef __attribute__((ext_vector_type(4))) unsigned int u32x4;

#define NB 2
#define NL 2048
#define ND 768
#define NH 12
#define NDK 64
#define NM 4096   // NB*NL
#define LOG2E 1.4426950408889634f

__device__ __forceinline__ unsigned short f2bf(float f) {
  unsigned u = __builtin_bit_cast(unsigned, f);
  u += 0x7FFFu + ((u >> 16) & 1u);          // RNE
  return (unsigned short)(u >> 16);
}

__device__ __forceinline__ float fexp2(float x) {
  float r;
  asm("v_exp_f32 %0, %1" : "=v"(r) : "v"(x));
  return r;
}

__device__ __forceinline__ float xmax32(float x) { return fmaxf(x, __shfl_xor(x, 32)); }
__device__ __forceinline__ float xsum32(float x) { return x + __shfl_xor(x, 32); }

__device__ __forceinline__ void gl_lds16(const unsigned short* g, unsigned short* l) {
  __builtin_amdgcn_global_load_lds((const __attribute__((address_space(1))) void*)g,
                                   (__attribute__((address_space(3))) void*)l, 16, 0, 0);
}

// ---- merged prep: conv (0..6143) | wt (6144..8447) | bias (8448..8639) | maskadd (8640..8641)
__global__ __launch_bounds__(256) void k_prep(const float* __restrict__ query,
                                              const float* __restrict__ keyval,
                                              const float* __restrict__ Wq,
                                              const float* __restrict__ Wk,
                                              const float* __restrict__ Wv,
                                              const float* __restrict__ Wo,
                                              const float* __restrict__ rel_emb,
                                              const int* __restrict__ mask,
                                              unsigned short* __restrict__ q_bf,
                                              unsigned short* __restrict__ kv_bf,
                                              unsigned short* __restrict__ Wq_t,
                                              unsigned short* __restrict__ Wk_t,
                                              unsigned short* __restrict__ Wv_t,
                                              unsigned short* __restrict__ Wo_t,
                                              float* __restrict__ bias_tab,
                                              float* __restrict__ maskadd,
                                              int* __restrict__ maskall) {
  __shared__ float shbuf[32 * 33];
  int blk = blockIdx.x, tid = threadIdx.x;
  if (blk < 6144) {
    int y = blk / 3072;
    int i = (blk - y * 3072) * 256 + tid;
    const float* src = y ? keyval : query;
    unsigned short* dst = y ? kv_bf : q_bf;
    float4 v = ((const float4*)src)[i];
    ushort4 o;
    o.x = f2bf(v.x); o.y = f2bf(v.y); o.z = f2bf(v.z); o.w = f2bf(v.w);
    ((ushort4*)dst)[i] = o;
  } else if (blk < 8448) {
    int rel = blk - 6144;
    int z = rel / 576, r2 = rel - z * 576;
    int bx = (r2 % 24) * 32, by = (r2 / 24) * 32;
    const float* w = (z == 0) ? Wq : (z == 1) ? Wk : (z == 2) ? Wv : Wo;
    unsigned short* o = (z == 0) ? Wq_t : (z == 1) ? Wk_t : (z == 2) ? Wv_t : Wo_t;
    float scale = (z == 0) ? 0.125f * LOG2E : 1.0f;
    int tx = tid & 31, ty = tid >> 5;
    float (*t)[33] = (float(*)[33])shbuf;
    for (int r = 0; r < 32; r += 8)
      t[ty + r][tx] = w[(by + ty + r) * ND + bx + tx];
    __syncthreads();
    for (int r = 0; r < 32; r += 8)
      o[(bx + ty + r) * ND + by + tx] = f2bf(t[tx][ty + r] * scale);
  } else if (blk < 8640) {
    int idx = (blk - 8448) * 256 + tid;
    if (idx >= 4095 * NH) return;
    int h = idx % NH;
    int di = idx / NH;
    int rel = di - 2047;          // rel = k - q
    int n = -rel;
    int ret = 0;
    if (n < 0) { ret = 16; n = -n; }
    int b;
    if (n < 8) {
      b = ret + n;
    } else {
      int v = (n >= 91) ? 7 : (n >= 64) ? 6 : (n >= 46) ? 5 : (n >= 32) ? 4
            : (n >= 23) ? 3 : (n >= 16) ? 2 : (n >= 12) ? 1 : 0;
      b = ret + 8 + v;
    }
    bias_tab[h * 4095 + di] = rel_emb[b * NH + h] * LOG2E;
  } else {
    int b = blk - 8640;
    int* red = (int*)shbuf;
    int acc = 1;
    for (int i = tid; i < NL; i += 256) {
      int m = mask[b * NL + i];
      maskadd[b * NL + i] = m ? 0.0f : -1e30f;
      acc &= (m != 0) ? 1 : 0;
    }
    red[tid] = acc;
    __syncthreads();
    for (int s2 = 128; s2 > 0; s2 >>= 1) {
      if (tid < s2) red[tid] &= red[tid + s2];
      __syncthreads();
    }
    if (tid == 0) maskall[b] = red[0];
  }
}

// ---- fused QKV GEMM, 128x128 tile: grid (32, 18); y/6 = {Q,K,V}. BK=64, gl_lds w16.
__global__ __launch_bounds__(256) void k_gemm_qkv(const unsigned short* __restrict__ q_bf,
                                                  const unsigned short* __restrict__ kv_bf,
                                                  const unsigned short* __restrict__ Wt,
                                                  unsigned short* __restrict__ Qb,
                                                  unsigned short* __restrict__ Kb,
                                                  unsigned short* __restrict__ Vt) {
  __shared__ unsigned short As[8192];   // [128 rows][64 k], 16 KB
  __shared__ unsigned short Bs[8192];
  int tid = threadIdx.x;
  int wave = tid >> 6, lane = tid & 63;
  int lr = lane & 15, lg = lane >> 4;
  int m0 = blockIdx.x * 128;
  int z = blockIdx.y / 6;                  // 0=Q, 1=K, 2=V
  int nc0 = (blockIdx.y % 6) * 128;
  const unsigned short* A  = (z == 0) ? q_bf : kv_bf;
  const unsigned short* Bt = Wt + (size_t)blockIdx.y * 128 * ND;
  int wm = (wave >> 1) * 64, wn = (wave & 1) * 64;
  int srow = tid >> 3, spc = tid & 7;
  int sg = spc ^ (srow & 7);
  const unsigned short* Ag = A  + (size_t)(m0 + srow) * ND + sg * 8;
  const unsigned short* Bg = Bt + (size_t)srow * ND + sg * 8;
  f32x4 acc[4][4] = {};
  for (int t = 0; t < ND / 64; ++t) {
    int k0 = t * 64;
#pragma unroll
    for (int s = 0; s < 4; ++s) {
      gl_lds16(Ag + (size_t)(s * 32) * ND + k0, &As[s * 2048 + tid * 8]);
      gl_lds16(Bg + (size_t)(s * 32) * ND + k0, &Bs[s * 2048 + tid * 8]);
    }
    __syncthreads();
#pragma unroll
    for (int ks = 0; ks < 2; ++ks) {
      bf16x8 af[4], bfr[4];
#pragma unroll
      for (int i = 0; i < 4; ++i) {
        int ar = wm + i * 16 + lr;
        af[i] = *(const bf16x8*)&As[ar * 64 + (((ks * 4 + lg) ^ (ar & 7)) * 8)];
        int br = wn + i * 16 + lr;
        bfr[i] = *(const bf16x8*)&Bs[br * 64 + (((ks * 4 + lg) ^ (br & 7)) * 8)];
      }
#pragma unroll
      for (int mi = 0; mi < 4; ++mi)
#pragma unroll
        for (int ni = 0; ni < 4; ++ni)
          acc[mi][ni] = __builtin_amdgcn_mfma_f32_16x16x32_bf16(af[mi], bfr[ni], acc[mi][ni], 0, 0, 0);
    }
    __syncthreads();
  }
#pragma unroll
  for (int mi = 0; mi < 4; ++mi)
#pragma unroll
    for (int ni = 0; ni < 4; ++ni)
#pragma unroll
      for (int r = 0; r < 4; ++r) {
        int row = m0 + wm + mi * 16 + lg * 4 + r;
        int col = nc0 + wn + ni * 16 + lr;
        unsigned short v = f2bf(acc[mi][ni][r]);
        if (z == 0) {
          Qb[(size_t)row * ND + col] = v;
        } else if (z == 1) {
          Kb[(size_t)row * ND + col] = v;
        } else {
          int bb = row >> 11, l = row & 2047;
          Vt[(((size_t)bb * ND + col) << 11) + l] = v;
        }
      }
}

// ---- out-proj GEMM: C[M,N] fp32 = A[M,K] bf16 * Bt[N,K]^T. 128x64 tile, BK=64.
__global__ __launch_bounds__(256) void k_gemm(const unsigned short* __restrict__ A,
                                              const unsigned short* __restrict__ Bt,
                                              float* __restrict__ Cout,
                                              int Msz, int Nsz, int Ksz) {
  __shared__ unsigned short As[8192];
  __shared__ unsigned short Bs[4096];
  int tid = threadIdx.x;
  int wave = tid >> 6, lane = tid & 63;
  int lr = lane & 15, lg = lane >> 4;
  int m0 = blockIdx.x * 128, n0 = blockIdx.y * 64;
  int wm = (wave >> 1) * 64, wn = (wave & 1) * 32;
  int srow = tid >> 3, spc = tid & 7;
  int sg = spc ^ (srow & 7);
  const unsigned short* Ag = A  + (size_t)(m0 + srow) * Ksz + sg * 8;
  const unsigned short* Bg = Bt + (size_t)(n0 + srow) * Ksz + sg * 8;
  f32x4 acc[4][2] = {};
  for (int t = 0; t < Ksz / 64; ++t) {
    int k0 = t * 64;
#pragma unroll
    for (int s = 0; s < 4; ++s)
      gl_lds16(Ag + (size_t)(s * 32) * Ksz + k0, &As[s * 2048 + tid * 8]);
#pragma unroll
    for (int s = 0; s < 2; ++s)
      gl_lds16(Bg + (size_t)(s * 32) * Ksz + k0, &Bs[s * 2048 + tid * 8]);
    __syncthreads();
#pragma unroll
    for (int ks = 0; ks < 2; ++ks) {
      bf16x8 af[4], bfr[2];
#pragma unroll
      for (int i = 0; i < 4; ++i) {
        int ar = wm + i * 16 + lr;
        af[i] = *(const bf16x8*)&As[ar * 64 + (((ks * 4 + lg) ^ (ar & 7)) * 8)];
      }
#pragma unroll
      for (int i = 0; i < 2; ++i) {
        int br = wn + i * 16 + lr;
        bfr[i] = *(const bf16x8*)&Bs[br * 64 + (((ks * 4 + lg) ^ (br & 7)) * 8)];
      }
#pragma unroll
      for (int mi = 0; mi < 4; ++mi)
#pragma unroll
        for (int ni = 0; ni < 2; ++ni)
          acc[mi][ni] = __builtin_amdgcn_mfma_f32_16x16x32_bf16(af[mi], bfr[ni], acc[mi][ni], 0, 0, 0);
    }
    __syncthreads();
  }
#pragma unroll
  for (int mi = 0; mi < 4; ++mi)
#pragma unroll
    for (int ni = 0; ni < 2; ++ni)
#pragma unroll
      for (int r = 0; r < 4; ++r) {
        int row = m0 + wm + mi * 16 + lg * 4 + r;
        int col = n0 + wn + ni * 16 + lr;
        Cout[(size_t)row * Nsz + col] = acc[mi][ni][r];
      }
}

// ---- fused flash attention, split-KV: 8 waves/block; waves 0-3 = keys [0,1024),
// waves 4-7 = keys [1024,2048). Per-group K/V double-buffer + independent online
// softmax; LDS flash-combine at the end. Swapped-QK^T (exp2), far-tile zero-C bias,
// lane-local softmax common path. 2 blocks/CU x 8 waves = 16 waves/CU.
__global__ __launch_bounds__(512, 4) void k_attn(const unsigned short* __restrict__ Qb,
                                                 const unsigned short* __restrict__ Kb,
                                                 const unsigned short* __restrict__ Vt,
                                                 const float* __restrict__ bias_tab,
                                                 const float* __restrict__ maskadd,
                                                 const int* __restrict__ maskall,
                                                 unsigned short* __restrict__ Ob) {
  __shared__ unsigned short KV[2][2][2][4096];  // [grp][K/V][buf][8KB] = 64 KB
  __shared__ float biasw[384];                  // near band: biasw[d+191]
  int qt = blockIdx.x, bh = blockIdx.y;
  int b = bh / NH, h = bh % NH;
  int tid = threadIdx.x, wave = tid >> 6, lane = tid & 63;
  int grp = wave >> 2, w4 = wave & 3;
  int tg = tid & 255;                           // thread id within group
  int lr = lane & 15, lg = lane >> 4;
  int q0 = qt * 64;
  for (int i = tid; i < 383; i += 512) biasw[i] = bias_tab[h * 4095 + 1856 + i];
  float cFlo = bias_tab[h * 4095];          // d <= -91 saturated (bucket 15)
  float cFhi = bias_tab[h * 4095 + 4094];   // d >= +91 saturated (bucket 31)
  const unsigned short* Kbase = Kb + (size_t)(b * NL) * ND + h * NDK;
  const unsigned short* Vbase = Vt + (size_t)(b * NH + h) * NDK * NL;
  int srow = tg >> 3, spc = tg & 7;
  int sg = spc ^ (srow & 7);
  // key permutation: phys row srow stores logical key l0; +32 phys -> l0+4
  int l0 = (srow >> 4) * 32 + ((srow >> 2) & 3) * 8 + (srow & 3);
  const unsigned short* Kg0 = Kbase + (size_t)l0 * ND + sg * 8;
  const unsigned short* Kg1 = Kbase + (size_t)(l0 + 4) * ND + sg * 8;
  const unsigned short* Vg0 = Vbase + (size_t)srow * NL + sg * 8;
  const unsigned short* Vg1 = Vbase + (size_t)(32 + srow) * NL + sg * 8;
  bf16x8 aq[2];
  int qw = q0 + w4 * 16;
#pragma unroll
  for (int ks = 0; ks < 2; ++ks)
    aq[ks] = *(const bf16x8*)&Qb[(size_t)(b * NL + qw + lr) * ND + h * NDK + ks * 32 + lg * 8];
  const float* cbase = maskadd + b * NL;
  int nomask = __builtin_amdgcn_readfirstlane(maskall[b]);
  f32x4 accO[4] = {};
  float mst = -1e30f, lstl = 0.f;          // per-lane partial row-sum (16 keys/lane)
  int bconst = lg * 8 - w4 * 16 - lr + 191 - q0;   // near idx = kt*64 + subk + bconst
  int src0 = (lane & 48) | ((lane >> 2) & 12);
  const int IT = 16;                        // tiles per group
  // prologue: stage own group's tile 0 (kt = grp*16)
  {
    size_t kok = (size_t)(grp * IT) * 64 * ND;
    size_t kov = (size_t)(grp * IT) * 64;
    gl_lds16(Kg0 + kok, &KV[grp][0][0][tg * 8]);
    gl_lds16(Kg1 + kok, &KV[grp][0][0][2048 + tg * 8]);
    gl_lds16(Vg0 + kov, &KV[grp][1][0][tg * 8]);
    gl_lds16(Vg1 + kov, &KV[grp][1][0][2048 + tg * 8]);
  }
  __syncthreads();                           // biasw + tile 0 ready
  int cur = 0;
  for (int it = 0; it < IT; ++it) {
    int kt = grp * IT + it;
    float4 cv[2][2];
    if (!nomask) {
#pragma unroll
      for (int hf = 0; hf < 2; ++hf)
#pragma unroll
        for (int qd = 0; qd < 2; ++qd)
          cv[hf][qd] = *(const float4*)&cbase[kt * 64 + hf * 32 + lg * 8 + qd * 4];
    }
    if (it + 1 < IT) {                       // stage next tile into other buffer
      size_t kok = (size_t)(kt + 1) * 64 * ND;
      size_t kov = (size_t)(kt + 1) * 64;
      gl_lds16(Kg0 + kok, &KV[grp][0][cur ^ 1][tg * 8]);
      gl_lds16(Kg1 + kok, &KV[grp][0][cur ^ 1][2048 + tg * 8]);
      gl_lds16(Vg0 + kov, &KV[grp][1][cur ^ 1][tg * 8]);
      gl_lds16(Vg1 + kov, &KV[grp][1][cur ^ 1][2048 + tg * 8]);
    }
    const unsigned short* Ksb = KV[grp][0][cur];
    const unsigned short* Vsb = KV[grp][1][cur];
    int kt64 = kt * 64;
    bool farlo = (kt64 + 63 < q0 - 90), farhi = (kt64 > q0 + 153);
    float ctile = farlo ? cFlo : (farhi ? cFhi : 0.0f);
    f32x4 s[4];
    __builtin_amdgcn_s_setprio(1);
    if (nomask && (farlo || farhi)) {
      const f32x4 z = {0.f, 0.f, 0.f, 0.f};
#pragma unroll
      for (int ni = 0; ni < 4; ++ni) {
        int kr = ni * 16 + lr;
        bf16x8 bk0 = *(const bf16x8*)&Ksb[kr * 64 + ((lg ^ (lr & 7)) * 8)];
        bf16x8 bk1 = *(const bf16x8*)&Ksb[kr * 64 + (((4 + lg) ^ (lr & 7)) * 8)];
        s[ni] = __builtin_amdgcn_mfma_f32_16x16x32_bf16(bk0, aq[0], z, 0, 0, 0);
        s[ni] = __builtin_amdgcn_mfma_f32_16x16x32_bf16(bk1, aq[1], s[ni], 0, 0, 0);
      }
    } else {
      if (farlo || farhi) {
#pragma unroll
        for (int ni = 0; ni < 4; ++ni)
#pragma unroll
          for (int r = 0; r < 4; ++r) s[ni][r] = 0.f;   // ctile folded later
      } else {
#pragma unroll
        for (int ni = 0; ni < 4; ++ni)
#pragma unroll
          for (int r = 0; r < 4; ++r)
            s[ni][r] = biasw[kt64 + (ni & 1) * 32 + (ni >> 1) * 4 + r + bconst];
      }
      if (!nomask) {
#pragma unroll
        for (int ni = 0; ni < 4; ++ni)
#pragma unroll
          for (int r = 0; r < 4; ++r)
            s[ni][r] += ((const float*)&cv[ni & 1][ni >> 1])[r];
      }
#pragma unroll
      for (int ni = 0; ni < 4; ++ni) {
        int kr = ni * 16 + lr;
        bf16x8 bk0 = *(const bf16x8*)&Ksb[kr * 64 + ((lg ^ (lr & 7)) * 8)];
        bf16x8 bk1 = *(const bf16x8*)&Ksb[kr * 64 + (((4 + lg) ^ (lr & 7)) * 8)];
        s[ni] = __builtin_amdgcn_mfma_f32_16x16x32_bf16(bk0, aq[0], s[ni], 0, 0, 0);
        s[ni] = __builtin_amdgcn_mfma_f32_16x16x32_bf16(bk1, aq[1], s[ni], 0, 0, 0);
      }
    }
    __builtin_amdgcn_s_setprio(0);
    // lane-local max (no cross-lane on common path)
    f32x4 t0, t1;
#pragma unroll
    for (int r = 0; r < 4; ++r) t0[r] = fmaxf(s[0][r], s[1][r]);
#pragma unroll
    for (int r = 0; r < 4; ++r) t1[r] = fmaxf(s[2][r], s[3][r]);
#pragma unroll
    for (int r = 0; r < 4; ++r) t0[r] = fmaxf(t0[r], t1[r]);
    float lm = fmaxf(fmaxf(t0[0], t0[1]), fmaxf(t0[2], t0[3]));
    if (!__all(lm + ctile - mst <= 8.0f)) {
      float pmax = fmaxf(lm, __shfl_xor(lm, 16));
      pmax = xmax32(pmax);
      float pm2 = pmax + ctile;
      float mnew = fmaxf(mst, pm2);
      float sc = fexp2(mst - mnew);
      float scB[4];
#pragma unroll
      for (int r = 0; r < 4; ++r) scB[r] = __shfl(sc, src0 | r);
#pragma unroll
      for (int ni = 0; ni < 4; ++ni)
#pragma unroll
        for (int r = 0; r < 4; ++r) accO[ni][r] *= scB[r];
      lstl *= sc;
      mst = mnew;
    }
    float msub = mst - ctile;
#pragma unroll
    for (int ni = 0; ni < 4; ++ni)
#pragma unroll
      for (int r = 0; r < 4; ++r) s[ni][r] = fexp2(s[ni][r] - msub);
    {
      f32x4 ta = s[0] + s[1];
      f32x4 tb = s[2] + s[3];
      ta = ta + tb;
      lstl += (ta[0] + ta[1]) + (ta[2] + ta[3]);
    }
    // pack P: lane's 16 values are exactly its PV A-fragments (key permutation)
    unsigned pw[8];
#pragma unroll
    for (int ni = 0; ni < 4; ++ni) {
      unsigned a, c;
      asm("v_cvt_pk_bf16_f32 %0, %1, %2" : "=v"(a) : "v"(s[ni][0]), "v"(s[ni][1]));
      asm("v_cvt_pk_bf16_f32 %0, %1, %2" : "=v"(c) : "v"(s[ni][2]), "v"(s[ni][3]));
      pw[ni * 2] = a; pw[ni * 2 + 1] = c;
    }
    u32x4 apw0 = {pw[0], pw[1], pw[4], pw[5]};
    u32x4 apw1 = {pw[2], pw[3], pw[6], pw[7]};
    bf16x8 ap0 = __builtin_bit_cast(bf16x8, apw0);
    bf16x8 ap1 = __builtin_bit_cast(bf16x8, apw1);
    __builtin_amdgcn_s_setprio(1);
#pragma unroll
    for (int ni = 0; ni < 4; ++ni) {
      int vr = ni * 16 + lr;
      bf16x8 bv0 = *(const bf16x8*)&Vsb[vr * 64 + ((lg ^ (lr & 7)) * 8)];
      bf16x8 bv1 = *(const bf16x8*)&Vsb[vr * 64 + (((4 + lg) ^ (lr & 7)) * 8)];
      accO[ni] = __builtin_amdgcn_mfma_f32_16x16x32_bf16(ap0, bv0, accO[ni], 0, 0, 0);
      accO[ni] = __builtin_amdgcn_mfma_f32_16x16x32_bf16(ap1, bv1, accO[ni], 0, 0, 0);
    }
    __builtin_amdgcn_s_setprio(0);
    __syncthreads();   // stage(t+1) drained + all reads of buf[cur] done
    cur ^= 1;
  }
  // per-group row sum (row = lr)
  float lstg = lstl + __shfl_xor(lstl, 16);
  lstg = xsum32(lstg);
  // ---- flash-combine of the two groups through LDS (aliased over dead K/V bufs)
  float* Oarr = (float*)&KV[0][0][0][0];   // [64 rows][65] padded, 16.6 KB
  float* mArr = Oarr + 64 * 65;            // [64]
  float* lArr = mArr + 64;                 // [64]
  __syncthreads();                         // all main-loop LDS reads complete
  if (grp == 1) {
#pragma unroll
    for (int ni = 0; ni < 4; ++ni)
#pragma unroll
      for (int r = 0; r < 4; ++r)
        Oarr[(w4 * 16 + lg * 4 + r) * 65 + ni * 16 + lr] = accO[ni][r];
    if (lane < 16) { mArr[w4 * 16 + lane] = mst; lArr[w4 * 16 + lane] = lstg; }
  }
  __syncthreads();
  if (grp == 0) {
    float m1 = mArr[w4 * 16 + lr];
    float l1 = lArr[w4 * 16 + lr];
    float m = fmaxf(mst, m1);
    float w0 = fexp2(mst - m), w1 = fexp2(m1 - m);
    float lcomb = lstg * w0 + l1 * w1;
    float linv = 1.0f / lcomb;
    float w0B[4], w1B[4], lB[4];
#pragma unroll
    for (int r = 0; r < 4; ++r) {
      w0B[r] = __shfl(w0, src0 | r);
      w1B[r] = __shfl(w1, src0 | r);
      lB[r]  = __shfl(linv, src0 | r);
    }
#pragma unroll
    for (int ni = 0; ni < 4; ++ni)
#pragma unroll
      for (int r = 0; r < 4; ++r) {
        float o1 = Oarr[(w4 * 16 + lg * 4 + r) * 65 + ni * 16 + lr];
        float v = (accO[ni][r] * w0B[r] + o1 * w1B[r]) * lB[r];
        int qg = qw + lg * 4 + r;
        int col = h * NDK + ni * 16 + lr;
        Ob[(size_t)(b * NL + qg) * ND + col] = f2bf(v);
      }
  }
}

extern "C" void kernel_launch(void* const* d_in, const int* in_sizes, int n_in,
                              void* d_out, int out_size, void* d_ws, size_t ws_size,
                              hipStream_t stream) {
  const float* query  = (const float*)d_in[0];
  const float* keyval = (const float*)d_in[1];
  const int*   mask   = (const int*)d_in[2];
  const float* Wq     = (const float*)d_in[3];
  const float* Wk     = (const float*)d_in[4];
  const float* Wv     = (const float*)d_in[5];
  const float* Wo     = (const float*)d_in[6];
  const float* rel    = (const float*)d_in[7];

  char* ws = (char*)d_ws;
  unsigned short* q_bf  = (unsigned short*)(ws);              // 4096x768 bf16
  unsigned short* kv_bf = (unsigned short*)(ws + 6291456);
  unsigned short* Wq_t  = (unsigned short*)(ws + 12582912);   // [N][K] bf16 (x 0.125*log2e)
  unsigned short* Wk_t  = (unsigned short*)(ws + 13762560);
  unsigned short* Wv_t  = (unsigned short*)(ws + 14942208);
  unsigned short* Wo_t  = (unsigned short*)(ws + 16121856);
  unsigned short* Qb    = (unsigned short*)(ws + 17301504);   // [B,L,H,DK]
  unsigned short* Kb    = (unsigned short*)(ws + 23592960);
  unsigned short* Vt    = (unsigned short*)(ws + 29884416);   // [B,768,L]
  unsigned short* Ob    = (unsigned short*)(ws + 36175872);   // [B,L,H*DK]
  float* bias_tab       = (float*)(ws + 42467328);            // [H][4095], x log2e
  float* maskadd        = (float*)(ws + 42663936);            // [B][L]
  int*   maskall        = (int*)(ws + 42680320);              // [B]

  k_prep<<<dim3(8642), dim3(256), 0, stream>>>(query, keyval, Wq, Wk, Wv, Wo, rel, mask,
                                               q_bf, kv_bf, Wq_t, Wk_t, Wv_t, Wo_t,
                                               bias_tab, maskadd, maskall);
  k_gemm_qkv<<<dim3(32, 18), dim3(256), 0, stream>>>(q_bf, kv_bf, Wq_t, Qb, Kb, Vt);
  k_attn<<<dim3(32, 24), dim3(512), 0, stream>>>(Qb, Kb, Vt, bias_tab, maskadd, maskall, Ob);
  k_gemm<<<dim3(32, 12), dim3(256), 0, stream>>>(Ob, Wo_t, (float*)d_out, NM, ND, ND);
}

// Round 12
// 114.527 us; speedup vs baseline: 1.0259x; 1.0259x over previous
//
#include <hip/hip_runtime.h>
#include <stdint.h>

typedef __attribute__((ext_vector_type(8))) short bf16x8;
typedef __attribute__((ext_vector_type(4))) float f32x4;
typedef __attribute__((ext_vector_type(4))) unsigned int u32x4;

#define NB 2
#define NL 2048
#define ND 768
#define NH 12
#define NDK 64
#define NM 4096   // NB*NL
#define LOG2E 1.4426950408889634f

__device__ __forceinline__ unsigned short f2bf(float f) {
  unsigned u = __builtin_bit_cast(unsigned, f);
  u += 0x7FFFu + ((u >> 16) & 1u);          // RNE
  return (unsigned short)(u >> 16);
}

__device__ __forceinline__ float fexp2(float x) {
  float r;
  asm("v_exp_f32 %0, %1" : "=v"(r) : "v"(x));
  return r;
}

__device__ __forceinline__ float xmax32(float x) { return fmaxf(x, __shfl_xor(x, 32)); }
__device__ __forceinline__ float xsum32(float x) { return x + __shfl_xor(x, 32); }

__device__ __forceinline__ void gl_lds16(const unsigned short* g, unsigned short* l) {
  __builtin_amdgcn_global_load_lds((const __attribute__((address_space(1))) void*)g,
                                   (__attribute__((address_space(3))) void*)l, 16, 0, 0);
}

// ---- merged prep: conv (0..6143) | wt (6144..8447) | bias (8448..8639) | maskadd (8640..8641)
__global__ __launch_bounds__(256) void k_prep(const float* __restrict__ query,
                                              const float* __restrict__ keyval,
                                              const float* __restrict__ Wq,
                                              const float* __restrict__ Wk,
                                              const float* __restrict__ Wv,
                                              const float* __restrict__ Wo,
                                              const float* __restrict__ rel_emb,
                                              const int* __restrict__ mask,
                                              unsigned short* __restrict__ q_bf,
                                              unsigned short* __restrict__ kv_bf,
                                              unsigned short* __restrict__ Wq_t,
                                              unsigned short* __restrict__ Wk_t,
                                              unsigned short* __restrict__ Wv_t,
                                              unsigned short* __restrict__ Wo_t,
                                              float* __restrict__ bias_tab,
                                              float* __restrict__ maskadd,
                                              int* __restrict__ maskall) {
  __shared__ float shbuf[32 * 33];
  int blk = blockIdx.x, tid = threadIdx.x;
  if (blk < 6144) {
    int y = blk / 3072;
    int i = (blk - y * 3072) * 256 + tid;
    const float* src = y ? keyval : query;
    unsigned short* dst = y ? kv_bf : q_bf;
    float4 v = ((const float4*)src)[i];
    ushort4 o;
    o.x = f2bf(v.x); o.y = f2bf(v.y); o.z = f2bf(v.z); o.w = f2bf(v.w);
    ((ushort4*)dst)[i] = o;
  } else if (blk < 8448) {
    int rel = blk - 6144;
    int z = rel / 576, r2 = rel - z * 576;
    int bx = (r2 % 24) * 32, by = (r2 / 24) * 32;
    const float* w = (z == 0) ? Wq : (z == 1) ? Wk : (z == 2) ? Wv : Wo;
    unsigned short* o = (z == 0) ? Wq_t : (z == 1) ? Wk_t : (z == 2) ? Wv_t : Wo_t;
    float scale = (z == 0) ? 0.125f * LOG2E : 1.0f;
    int tx = tid & 31, ty = tid >> 5;
    float (*t)[33] = (float(*)[33])shbuf;
    for (int r = 0; r < 32; r += 8)
      t[ty + r][tx] = w[(by + ty + r) * ND + bx + tx];
    __syncthreads();
    for (int r = 0; r < 32; r += 8)
      o[(bx + ty + r) * ND + by + tx] = f2bf(t[tx][ty + r] * scale);
  } else if (blk < 8640) {
    int idx = (blk - 8448) * 256 + tid;
    if (idx >= 4095 * NH) return;
    int h = idx % NH;
    int di = idx / NH;
    int rel = di - 2047;          // rel = k - q
    int n = -rel;
    int ret = 0;
    if (n < 0) { ret = 16; n = -n; }
    int b;
    if (n < 8) {
      b = ret + n;
    } else {
      int v = (n >= 91) ? 7 : (n >= 64) ? 6 : (n >= 46) ? 5 : (n >= 32) ? 4
            : (n >= 23) ? 3 : (n >= 16) ? 2 : (n >= 12) ? 1 : 0;
      b = ret + 8 + v;
    }
    bias_tab[h * 4095 + di] = rel_emb[b * NH + h] * LOG2E;
  } else {
    int b = blk - 8640;
    int* red = (int*)shbuf;
    int acc = 1;
    for (int i = tid; i < NL; i += 256) {
      int m = mask[b * NL + i];
      maskadd[b * NL + i] = m ? 0.0f : -1e30f;
      acc &= (m != 0) ? 1 : 0;
    }
    red[tid] = acc;
    __syncthreads();
    for (int s2 = 128; s2 > 0; s2 >>= 1) {
      if (tid < s2) red[tid] &= red[tid + s2];
      __syncthreads();
    }
    if (tid == 0) maskall[b] = red[0];
  }
}

// ---- fused QKV GEMM, 128x128 tile: grid (32, 18); y/6 = {Q,K,V}. BK=64, gl_lds w16.
__global__ __launch_bounds__(256) void k_gemm_qkv(const unsigned short* __restrict__ q_bf,
                                                  const unsigned short* __restrict__ kv_bf,
                                                  const unsigned short* __restrict__ Wt,
                                                  unsigned short* __restrict__ Qb,
                                                  unsigned short* __restrict__ Kb,
                                                  unsigned short* __restrict__ Vt) {
  __shared__ unsigned short As[8192];   // [128 rows][64 k], 16 KB
  __shared__ unsigned short Bs[8192];
  int tid = threadIdx.x;
  int wave = tid >> 6, lane = tid & 63;
  int lr = lane & 15, lg = lane >> 4;
  int m0 = blockIdx.x * 128;
  int z = blockIdx.y / 6;                  // 0=Q, 1=K, 2=V
  int nc0 = (blockIdx.y % 6) * 128;
  const unsigned short* A  = (z == 0) ? q_bf : kv_bf;
  const unsigned short* Bt = Wt + (size_t)blockIdx.y * 128 * ND;
  int wm = (wave >> 1) * 64, wn = (wave & 1) * 64;
  int srow = tid >> 3, spc = tid & 7;
  int sg = spc ^ (srow & 7);
  const unsigned short* Ag = A  + (size_t)(m0 + srow) * ND + sg * 8;
  const unsigned short* Bg = Bt + (size_t)srow * ND + sg * 8;
  f32x4 acc[4][4] = {};
  for (int t = 0; t < ND / 64; ++t) {
    int k0 = t * 64;
#pragma unroll
    for (int s = 0; s < 4; ++s) {
      gl_lds16(Ag + (size_t)(s * 32) * ND + k0, &As[s * 2048 + tid * 8]);
      gl_lds16(Bg + (size_t)(s * 32) * ND + k0, &Bs[s * 2048 + tid * 8]);
    }
    __syncthreads();
#pragma unroll
    for (int ks = 0; ks < 2; ++ks) {
      bf16x8 af[4], bfr[4];
#pragma unroll
      for (int i = 0; i < 4; ++i) {
        int ar = wm + i * 16 + lr;
        af[i] = *(const bf16x8*)&As[ar * 64 + (((ks * 4 + lg) ^ (ar & 7)) * 8)];
        int br = wn + i * 16 + lr;
        bfr[i] = *(const bf16x8*)&Bs[br * 64 + (((ks * 4 + lg) ^ (br & 7)) * 8)];
      }
#pragma unroll
      for (int mi = 0; mi < 4; ++mi)
#pragma unroll
        for (int ni = 0; ni < 4; ++ni)
          acc[mi][ni] = __builtin_amdgcn_mfma_f32_16x16x32_bf16(af[mi], bfr[ni], acc[mi][ni], 0, 0, 0);
    }
    __syncthreads();
  }
#pragma unroll
  for (int mi = 0; mi < 4; ++mi)
#pragma unroll
    for (int ni = 0; ni < 4; ++ni)
#pragma unroll
      for (int r = 0; r < 4; ++r) {
        int row = m0 + wm + mi * 16 + lg * 4 + r;
        int col = nc0 + wn + ni * 16 + lr;
        unsigned short v = f2bf(acc[mi][ni][r]);
        if (z == 0) {
          Qb[(size_t)row * ND + col] = v;
        } else if (z == 1) {
          Kb[(size_t)row * ND + col] = v;
        } else {
          int bb = row >> 11, l = row & 2047;
          Vt[(((size_t)bb * ND + col) << 11) + l] = v;
        }
      }
}

// ---- out-proj GEMM: C[M,N] fp32 = A[M,K] bf16 * Bt[N,K]^T. 128x64 tile, BK=64.
__global__ __launch_bounds__(256) void k_gemm(const unsigned short* __restrict__ A,
                                              const unsigned short* __restrict__ Bt,
                                              float* __restrict__ Cout,
                                              int Msz, int Nsz, int Ksz) {
  __shared__ unsigned short As[8192];
  __shared__ unsigned short Bs[4096];
  int tid = threadIdx.x;
  int wave = tid >> 6, lane = tid & 63;
  int lr = lane & 15, lg = lane >> 4;
  int m0 = blockIdx.x * 128, n0 = blockIdx.y * 64;
  int wm = (wave >> 1) * 64, wn = (wave & 1) * 32;
  int srow = tid >> 3, spc = tid & 7;
  int sg = spc ^ (srow & 7);
  const unsigned short* Ag = A  + (size_t)(m0 + srow) * Ksz + sg * 8;
  const unsigned short* Bg = Bt + (size_t)(n0 + srow) * Ksz + sg * 8;
  f32x4 acc[4][2] = {};
  for (int t = 0; t < Ksz / 64; ++t) {
    int k0 = t * 64;
#pragma unroll
    for (int s = 0; s < 4; ++s)
      gl_lds16(Ag + (size_t)(s * 32) * Ksz + k0, &As[s * 2048 + tid * 8]);
#pragma unroll
    for (int s = 0; s < 2; ++s)
      gl_lds16(Bg + (size_t)(s * 32) * Ksz + k0, &Bs[s * 2048 + tid * 8]);
    __syncthreads();
#pragma unroll
    for (int ks = 0; ks < 2; ++ks) {
      bf16x8 af[4], bfr[2];
#pragma unroll
      for (int i = 0; i < 4; ++i) {
        int ar = wm + i * 16 + lr;
        af[i] = *(const bf16x8*)&As[ar * 64 + (((ks * 4 + lg) ^ (ar & 7)) * 8)];
      }
#pragma unroll
      for (int i = 0; i < 2; ++i) {
        int br = wn + i * 16 + lr;
        bfr[i] = *(const bf16x8*)&Bs[br * 64 + (((ks * 4 + lg) ^ (br & 7)) * 8)];
      }
#pragma unroll
      for (int mi = 0; mi < 4; ++mi)
#pragma unroll
        for (int ni = 0; ni < 2; ++ni)
          acc[mi][ni] = __builtin_amdgcn_mfma_f32_16x16x32_bf16(af[mi], bfr[ni], acc[mi][ni], 0, 0, 0);
    }
    __syncthreads();
  }
#pragma unroll
  for (int mi = 0; mi < 4; ++mi)
#pragma unroll
    for (int ni = 0; ni < 2; ++ni)
#pragma unroll
      for (int r = 0; r < 4; ++r) {
        int row = m0 + wm + mi * 16 + lg * 4 + r;
        int col = n0 + wn + ni * 16 + lr;
        Cout[(size_t)row * Nsz + col] = acc[mi][ni][r];
      }
}

// ---- fused flash attention (R10 structure, reverted from split-KV): swapped-QK^T
// (exp2), 3-buffer counted-vmcnt pipeline, far-tile zero-C bias fold, lane-local
// softmax. NEW: V fragment ds_reads hoisted above the softmax so their LDS latency
// drains under the exp chain instead of stalling the PV MFMAs.
__global__ __launch_bounds__(256, 3) void k_attn(const unsigned short* __restrict__ Qb,
                                                 const unsigned short* __restrict__ Kb,
                                                 const unsigned short* __restrict__ Vt,
                                                 const float* __restrict__ bias_tab,
                                                 const float* __restrict__ maskadd,
                                                 const int* __restrict__ maskall,
                                                 unsigned short* __restrict__ Ob) {
  __shared__ unsigned short Ks[3][4096];   // [64 phys keys][64 dk], XOR-swizzled chunks
  __shared__ unsigned short Vs[3][4096];   // [64 dk][64 keys natural], XOR-swizzled
  __shared__ float biasw[384];             // near band: biasw[d+191]
  int qt = blockIdx.x, bh = blockIdx.y;
  int b = bh / NH, h = bh % NH;
  int tid = threadIdx.x, wave = tid >> 6, lane = tid & 63;
  int lr = lane & 15, lg = lane >> 4;
  int q0 = qt * 64;
  for (int i = tid; i < 383; i += 256) biasw[i] = bias_tab[h * 4095 + 1856 + i];
  float cFlo = bias_tab[h * 4095];          // d <= -91 saturated (bucket 15)
  float cFhi = bias_tab[h * 4095 + 4094];   // d >= +91 saturated (bucket 31)
  const unsigned short* Kbase = Kb + (size_t)(b * NL) * ND + h * NDK;
  const unsigned short* Vbase = Vt + (size_t)(b * NH + h) * NDK * NL;
  int srow = tid >> 3, spc = tid & 7;
  int sg = spc ^ (srow & 7);
  // key permutation: phys row srow stores logical key l0; +32 phys -> l0+4
  int l0 = (srow >> 4) * 32 + ((srow >> 2) & 3) * 8 + (srow & 3);
  const unsigned short* Kg0 = Kbase + (size_t)l0 * ND + sg * 8;
  const unsigned short* Kg1 = Kbase + (size_t)(l0 + 4) * ND + sg * 8;
  const unsigned short* Vg0 = Vbase + (size_t)srow * NL + sg * 8;
  const unsigned short* Vg1 = Vbase + (size_t)(32 + srow) * NL + sg * 8;
  bf16x8 aq[2];
  int qw = q0 + wave * 16;
#pragma unroll
  for (int ks = 0; ks < 2; ++ks)
    aq[ks] = *(const bf16x8*)&Qb[(size_t)(b * NL + qw + lr) * ND + h * NDK + ks * 32 + lg * 8];
  const float* cbase = maskadd + b * NL;
  int nomask = __builtin_amdgcn_readfirstlane(maskall[b]);
  f32x4 accO[4] = {};
  float mst = -1e30f, lstl = 0.f;          // per-lane partial row-sum (16 keys/lane)
  int bconst = lg * 8 - wave * 16 - lr + 191 - q0;   // near idx = kt*64 + subk + bconst
  int src0 = (lane & 48) | ((lane >> 2) & 12);
  // prologue: stage tiles 0 and 1 into bufs 0, 1 (8 loads in flight)
  gl_lds16(Kg0, &Ks[0][tid * 8]);
  gl_lds16(Kg1, &Ks[0][2048 + tid * 8]);
  gl_lds16(Vg0, &Vs[0][tid * 8]);
  gl_lds16(Vg1, &Vs[0][2048 + tid * 8]);
  {
    size_t kok = (size_t)64 * ND, kov = 64;
    gl_lds16(Kg0 + kok, &Ks[1][tid * 8]);
    gl_lds16(Kg1 + kok, &Ks[1][2048 + tid * 8]);
    gl_lds16(Vg0 + kov, &Vs[1][tid * 8]);
    gl_lds16(Vg1 + kov, &Vs[1][2048 + tid * 8]);
  }
  asm volatile("s_waitcnt vmcnt(4) lgkmcnt(0)" ::: "memory");  // tile0 + biasw ready
  __builtin_amdgcn_s_barrier();
  int cur = 0;
  const int NT = NL / 64;
  for (int kt = 0; kt < NT; ++kt) {
    float4 cv[2][2];
    if (!nomask) {
#pragma unroll
      for (int hf = 0; hf < 2; ++hf)
#pragma unroll
        for (int qd = 0; qd < 2; ++qd)
          cv[hf][qd] = *(const float4*)&cbase[kt * 64 + hf * 32 + lg * 8 + qd * 4];
    }
    bool pf = (kt + 2 < NT);
    if (pf) {
      int st = cur + 2; if (st >= 3) st -= 3;
      size_t kok = (size_t)(kt + 2) * 64 * ND;
      size_t kov = (size_t)(kt + 2) * 64;
      gl_lds16(Kg0 + kok, &Ks[st][tid * 8]);
      gl_lds16(Kg1 + kok, &Ks[st][2048 + tid * 8]);
      gl_lds16(Vg0 + kov, &Vs[st][tid * 8]);
      gl_lds16(Vg1 + kov, &Vs[st][2048 + tid * 8]);
    }
    int kt64 = kt * 64;
    bool farlo = (kt64 + 63 < q0 - 90), farhi = (kt64 > q0 + 153);
    float ctile = farlo ? cFlo : (farhi ? cFhi : 0.0f);
    f32x4 s[4];
    __builtin_amdgcn_s_setprio(1);
    if (nomask && (farlo || farhi)) {
      // far tile, no mask: MFMA from zero C; ctile folded into softmax scalars
      const f32x4 z = {0.f, 0.f, 0.f, 0.f};
#pragma unroll
      for (int ni = 0; ni < 4; ++ni) {
        int kr = ni * 16 + lr;
        bf16x8 bk0 = *(const bf16x8*)&Ks[cur][kr * 64 + ((lg ^ (lr & 7)) * 8)];
        bf16x8 bk1 = *(const bf16x8*)&Ks[cur][kr * 64 + (((4 + lg) ^ (lr & 7)) * 8)];
        s[ni] = __builtin_amdgcn_mfma_f32_16x16x32_bf16(bk0, aq[0], z, 0, 0, 0);
        s[ni] = __builtin_amdgcn_mfma_f32_16x16x32_bf16(bk1, aq[1], s[ni], 0, 0, 0);
      }
    } else {
      if (farlo || farhi) {
#pragma unroll
        for (int ni = 0; ni < 4; ++ni)
#pragma unroll
          for (int r = 0; r < 4; ++r) s[ni][r] = 0.f;   // ctile folded later
      } else {
#pragma unroll
        for (int ni = 0; ni < 4; ++ni)
#pragma unroll
          for (int r = 0; r < 4; ++r)
            s[ni][r] = biasw[kt64 + (ni & 1) * 32 + (ni >> 1) * 4 + r + bconst];
      }
      if (!nomask) {
#pragma unroll
        for (int ni = 0; ni < 4; ++ni)
#pragma unroll
          for (int r = 0; r < 4; ++r)
            s[ni][r] += ((const float*)&cv[ni & 1][ni >> 1])[r];
      }
#pragma unroll
      for (int ni = 0; ni < 4; ++ni) {
        int kr = ni * 16 + lr;
        bf16x8 bk0 = *(const bf16x8*)&Ks[cur][kr * 64 + ((lg ^ (lr & 7)) * 8)];
        bf16x8 bk1 = *(const bf16x8*)&Ks[cur][kr * 64 + (((4 + lg) ^ (lr & 7)) * 8)];
        s[ni] = __builtin_amdgcn_mfma_f32_16x16x32_bf16(bk0, aq[0], s[ni], 0, 0, 0);
        s[ni] = __builtin_amdgcn_mfma_f32_16x16x32_bf16(bk1, aq[1], s[ni], 0, 0, 0);
      }
    }
    __builtin_amdgcn_s_setprio(0);
    // V fragments hoisted: issue now so LDS latency drains under the softmax
    bf16x8 bv0a[4], bv1a[4];
#pragma unroll
    for (int ni = 0; ni < 4; ++ni) {
      int vr = ni * 16 + lr;
      bv0a[ni] = *(const bf16x8*)&Vs[cur][vr * 64 + ((lg ^ (lr & 7)) * 8)];
      bv1a[ni] = *(const bf16x8*)&Vs[cur][vr * 64 + (((4 + lg) ^ (lr & 7)) * 8)];
    }
    // lane-local max over this lane's 16 keys (NO cross-lane on common path)
    f32x4 t0, t1;
#pragma unroll
    for (int r = 0; r < 4; ++r) t0[r] = fmaxf(s[0][r], s[1][r]);
#pragma unroll
    for (int r = 0; r < 4; ++r) t1[r] = fmaxf(s[2][r], s[3][r]);
#pragma unroll
    for (int r = 0; r < 4; ++r) t0[r] = fmaxf(t0[r], t1[r]);
    float lm = fmaxf(fmaxf(t0[0], t0[1]), fmaxf(t0[2], t0[3]));
    // defer-check: __all over lanes covers every row's max — equivalent condition
    if (!__all(lm + ctile - mst <= 8.0f)) {
      float pmax = fmaxf(lm, __shfl_xor(lm, 16));
      pmax = xmax32(pmax);
      float pm2 = pmax + ctile;
      float mnew = fmaxf(mst, pm2);
      float sc = fexp2(mst - mnew);
      float scB[4];
#pragma unroll
      for (int r = 0; r < 4; ++r) scB[r] = __shfl(sc, src0 | r);
#pragma unroll
      for (int ni = 0; ni < 4; ++ni)
#pragma unroll
        for (int r = 0; r < 4; ++r) accO[ni][r] *= scB[r];
      lstl *= sc;            // per-lane partial scales by its row's (uniform) sc
      mst = mnew;
    }
    float msub = mst - ctile;
#pragma unroll
    for (int ni = 0; ni < 4; ++ni)
#pragma unroll
      for (int r = 0; r < 4; ++r) s[ni][r] = fexp2(s[ni][r] - msub);
    // lane-local partial sum (cross-lane reduce deferred to epilogue)
    {
      f32x4 ta = s[0] + s[1];
      f32x4 tb = s[2] + s[3];
      ta = ta + tb;
      lstl += (ta[0] + ta[1]) + (ta[2] + ta[3]);
    }
    // pack P: lane's 16 values are exactly its PV A-fragments (key permutation)
    unsigned pw[8];
#pragma unroll
    for (int ni = 0; ni < 4; ++ni) {
      unsigned a, c;
      asm("v_cvt_pk_bf16_f32 %0, %1, %2" : "=v"(a) : "v"(s[ni][0]), "v"(s[ni][1]));
      asm("v_cvt_pk_bf16_f32 %0, %1, %2" : "=v"(c) : "v"(s[ni][2]), "v"(s[ni][3]));
      pw[ni * 2] = a; pw[ni * 2 + 1] = c;
    }
    u32x4 apw0 = {pw[0], pw[1], pw[4], pw[5]};
    u32x4 apw1 = {pw[2], pw[3], pw[6], pw[7]};
    bf16x8 ap0 = __builtin_bit_cast(bf16x8, apw0);
    bf16x8 ap1 = __builtin_bit_cast(bf16x8, apw1);
    // O += P @ V (operands already resident)
    __builtin_amdgcn_s_setprio(1);
#pragma unroll
    for (int ni = 0; ni < 4; ++ni) {
      accO[ni] = __builtin_amdgcn_mfma_f32_16x16x32_bf16(ap0, bv0a[ni], accO[ni], 0, 0, 0);
      accO[ni] = __builtin_amdgcn_mfma_f32_16x16x32_bf16(ap1, bv1a[ni], accO[ni], 0, 0, 0);
    }
    __builtin_amdgcn_s_setprio(0);
    // counted wait: stage(t+1) complete, stage(t+2)'s 4 loads stay in flight
    if (pf) asm volatile("s_waitcnt vmcnt(4)" ::: "memory");
    else    asm volatile("s_waitcnt vmcnt(0)" ::: "memory");
    __builtin_amdgcn_s_barrier();
    cur = (cur == 2) ? 0 : cur + 1;
  }
  // epilogue: one cross-lane row-sum, then broadcast 1/l to accO's row layout
  float lst = lstl + __shfl_xor(lstl, 16);
  lst = xsum32(lst);
  float linv = 1.0f / lst;
  float lB[4];
#pragma unroll
  for (int r = 0; r < 4; ++r) lB[r] = __shfl(linv, src0 | r);
#pragma unroll
  for (int ni = 0; ni < 4; ++ni)
#pragma unroll
    for (int r = 0; r < 4; ++r) {
      int qg = qw + lg * 4 + r;
      int col = h * NDK + ni * 16 + lr;
      Ob[(size_t)(b * NL + qg) * ND + col] = f2bf(accO[ni][r] * lB[r]);
    }
}

extern "C" void kernel_launch(void* const* d_in, const int* in_sizes, int n_in,
                              void* d_out, int out_size, void* d_ws, size_t ws_size,
                              hipStream_t stream) {
  const float* query  = (const float*)d_in[0];
  const float* keyval = (const float*)d_in[1];
  const int*   mask   = (const int*)d_in[2];
  const float* Wq     = (const float*)d_in[3];
  const float* Wk     = (const float*)d_in[4];
  const float* Wv     = (const float*)d_in[5];
  const float* Wo     = (const float*)d_in[6];
  const float* rel    = (const float*)d_in[7];

  char* ws = (char*)d_ws;
  unsigned short* q_bf  = (unsigned short*)(ws);              // 4096x768 bf16
  unsigned short* kv_bf = (unsigned short*)(ws + 6291456);
  unsigned short* Wq_t  = (unsigned short*)(ws + 12582912);   // [N][K] bf16 (x 0.125*log2e)
  unsigned short* Wk_t  = (unsigned short*)(ws + 13762560);
  unsigned short* Wv_t  = (unsigned short*)(ws + 14942208);
  unsigned short* Wo_t  = (unsigned short*)(ws + 16121856);
  unsigned short* Qb    = (unsigned short*)(ws + 17301504);   // [B,L,H,DK]
  unsigned short* Kb    = (unsigned short*)(ws + 23592960);
  unsigned short* Vt    = (unsigned short*)(ws + 29884416);   // [B,768,L]
  unsigned short* Ob    = (unsigned short*)(ws + 36175872);   // [B,L,H*DK]
  float* bias_tab       = (float*)(ws + 42467328);            // [H][4095], x log2e
  float* maskadd        = (float*)(ws + 42663936);            // [B][L]
  int*   maskall        = (int*)(ws + 42680320);              // [B]

  k_prep<<<dim3(8642), dim3(256), 0, stream>>>(query, keyval, Wq, Wk, Wv, Wo, rel, mask,
                                               q_bf, kv_bf, Wq_t, Wk_t, Wv_t, Wo_t,
                                               bias_tab, maskadd, maskall);
  k_gemm_qkv<<<dim3(32, 18), dim3(256), 0, stream>>>(q_bf, kv_bf, Wq_t, Qb, Kb, Vt);
  k_attn<<<dim3(32, 24), dim3(256), 0, stream>>>(Qb, Kb, Vt, bias_tab, maskadd, maskall, Ob);
  k_gemm<<<dim3(32, 12), dim3(256), 0, stream>>>(Ob, Wo_t, (float*)d_out, NM, ND, ND);
}

// Round 13
// 105.656 us; speedup vs baseline: 1.1120x; 1.0840x over previous
//
#include <hip/hip_runtime.h>
#include <stdint.h>

typedef __attribute__((ext_vector_type(8))) short bf16x8;
typedef __attribute__((ext_vector_type(4))) float f32x4;
typedef __attribute__((ext_vector_type(4))) unsigned int u32x4;

#define NB 2
#define NL 2048
#define ND 768
#define NH 12
#define NDK 64
#define NM 4096   // NB*NL
#define LOG2E 1.4426950408889634f

__device__ __forceinline__ unsigned short f2bf(float f) {
  unsigned u = __builtin_bit_cast(unsigned, f);
  u += 0x7FFFu + ((u >> 16) & 1u);          // RNE
  return (unsigned short)(u >> 16);
}

__device__ __forceinline__ float fexp2(float x) {
  float r;
  asm("v_exp_f32 %0, %1" : "=v"(r) : "v"(x));
  return r;
}

__device__ __forceinline__ float xmax32(float x) { return fmaxf(x, __shfl_xor(x, 32)); }
__device__ __forceinline__ float xsum32(float x) { return x + __shfl_xor(x, 32); }

__device__ __forceinline__ void gl_lds16(const unsigned short* g, unsigned short* l) {
  __builtin_amdgcn_global_load_lds((const __attribute__((address_space(1))) void*)g,
                                   (__attribute__((address_space(3))) void*)l, 16, 0, 0);
}

// ---- merged prep: conv (0..6143) | wt (6144..8447) | bias (8448..8639) | maskadd (8640..8641)
__global__ __launch_bounds__(256) void k_prep(const float* __restrict__ query,
                                              const float* __restrict__ keyval,
                                              const float* __restrict__ Wq,
                                              const float* __restrict__ Wk,
                                              const float* __restrict__ Wv,
                                              const float* __restrict__ Wo,
                                              const float* __restrict__ rel_emb,
                                              const int* __restrict__ mask,
                                              unsigned short* __restrict__ q_bf,
                                              unsigned short* __restrict__ kv_bf,
                                              unsigned short* __restrict__ Wq_t,
                                              unsigned short* __restrict__ Wk_t,
                                              unsigned short* __restrict__ Wv_t,
                                              unsigned short* __restrict__ Wo_t,
                                              float* __restrict__ bias_tab,
                                              float* __restrict__ maskadd,
                                              int* __restrict__ maskall) {
  __shared__ float shbuf[32 * 33];
  int blk = blockIdx.x, tid = threadIdx.x;
  if (blk < 6144) {
    int y = blk / 3072;
    int i = (blk - y * 3072) * 256 + tid;
    const float* src = y ? keyval : query;
    unsigned short* dst = y ? kv_bf : q_bf;
    float4 v = ((const float4*)src)[i];
    ushort4 o;
    o.x = f2bf(v.x); o.y = f2bf(v.y); o.z = f2bf(v.z); o.w = f2bf(v.w);
    ((ushort4*)dst)[i] = o;
  } else if (blk < 8448) {
    int rel = blk - 6144;
    int z = rel / 576, r2 = rel - z * 576;
    int bx = (r2 % 24) * 32, by = (r2 / 24) * 32;
    const float* w = (z == 0) ? Wq : (z == 1) ? Wk : (z == 2) ? Wv : Wo;
    unsigned short* o = (z == 0) ? Wq_t : (z == 1) ? Wk_t : (z == 2) ? Wv_t : Wo_t;
    float scale = (z == 0) ? 0.125f * LOG2E : 1.0f;
    int tx = tid & 31, ty = tid >> 5;
    float (*t)[33] = (float(*)[33])shbuf;
    for (int r = 0; r < 32; r += 8)
      t[ty + r][tx] = w[(by + ty + r) * ND + bx + tx];
    __syncthreads();
    for (int r = 0; r < 32; r += 8)
      o[(bx + ty + r) * ND + by + tx] = f2bf(t[tx][ty + r] * scale);
  } else if (blk < 8640) {
    int idx = (blk - 8448) * 256 + tid;
    if (idx >= 4095 * NH) return;
    int h = idx % NH;
    int di = idx / NH;
    int rel = di - 2047;          // rel = k - q
    int n = -rel;
    int ret = 0;
    if (n < 0) { ret = 16; n = -n; }
    int b;
    if (n < 8) {
      b = ret + n;
    } else {
      int v = (n >= 91) ? 7 : (n >= 64) ? 6 : (n >= 46) ? 5 : (n >= 32) ? 4
            : (n >= 23) ? 3 : (n >= 16) ? 2 : (n >= 12) ? 1 : 0;
      b = ret + 8 + v;
    }
    bias_tab[h * 4095 + di] = rel_emb[b * NH + h] * LOG2E;
  } else {
    int b = blk - 8640;
    int* red = (int*)shbuf;
    int acc = 1;
    for (int i = tid; i < NL; i += 256) {
      int m = mask[b * NL + i];
      maskadd[b * NL + i] = m ? 0.0f : -1e30f;
      acc &= (m != 0) ? 1 : 0;
    }
    red[tid] = acc;
    __syncthreads();
    for (int s2 = 128; s2 > 0; s2 >>= 1) {
      if (tid < s2) red[tid] &= red[tid + s2];
      __syncthreads();
    }
    if (tid == 0) maskall[b] = red[0];
  }
}

// ---- fused QKV GEMM, 128x128 tile: grid (32, 18); y/6 = {Q,K,V}. BK=64, gl_lds w16.
// V blocks (z==2) transpose their tile through LDS so Vt stores are 256B-coalesced
// (the old path did 2B stores at 4KB stride: 64 lines/instr, ~400MB of L2 RMW).
__global__ __launch_bounds__(256) void k_gemm_qkv(const unsigned short* __restrict__ q_bf,
                                                  const unsigned short* __restrict__ kv_bf,
                                                  const unsigned short* __restrict__ Wt,
                                                  unsigned short* __restrict__ Qb,
                                                  unsigned short* __restrict__ Kb,
                                                  unsigned short* __restrict__ Vt) {
  __shared__ unsigned short S[16384];   // A: [0,8192), B: [8192,16384); 32 KB
  unsigned short* As = S;
  unsigned short* Bs = S + 8192;
  int tid = threadIdx.x;
  int wave = tid >> 6, lane = tid & 63;
  int lr = lane & 15, lg = lane >> 4;
  int m0 = blockIdx.x * 128;
  int z = blockIdx.y / 6;                  // 0=Q, 1=K, 2=V
  int nc0 = (blockIdx.y % 6) * 128;
  const unsigned short* A  = (z == 0) ? q_bf : kv_bf;
  const unsigned short* Bt = Wt + (size_t)blockIdx.y * 128 * ND;
  int wm = (wave >> 1) * 64, wn = (wave & 1) * 64;
  int srow = tid >> 3, spc = tid & 7;
  int sg = spc ^ (srow & 7);
  const unsigned short* Ag = A  + (size_t)(m0 + srow) * ND + sg * 8;
  const unsigned short* Bg = Bt + (size_t)srow * ND + sg * 8;
  f32x4 acc[4][4] = {};
  for (int t = 0; t < ND / 64; ++t) {
    int k0 = t * 64;
#pragma unroll
    for (int s = 0; s < 4; ++s) {
      gl_lds16(Ag + (size_t)(s * 32) * ND + k0, &As[s * 2048 + tid * 8]);
      gl_lds16(Bg + (size_t)(s * 32) * ND + k0, &Bs[s * 2048 + tid * 8]);
    }
    __syncthreads();
#pragma unroll
    for (int ks = 0; ks < 2; ++ks) {
      bf16x8 af[4], bfr[4];
#pragma unroll
      for (int i = 0; i < 4; ++i) {
        int ar = wm + i * 16 + lr;
        af[i] = *(const bf16x8*)&As[ar * 64 + (((ks * 4 + lg) ^ (ar & 7)) * 8)];
        int br = wn + i * 16 + lr;
        bfr[i] = *(const bf16x8*)&Bs[br * 64 + (((ks * 4 + lg) ^ (br & 7)) * 8)];
      }
#pragma unroll
      for (int mi = 0; mi < 4; ++mi)
#pragma unroll
        for (int ni = 0; ni < 4; ++ni)
          acc[mi][ni] = __builtin_amdgcn_mfma_f32_16x16x32_bf16(af[mi], bfr[ni], acc[mi][ni], 0, 0, 0);
    }
    __syncthreads();
  }
  if (z == 2) {
    // transpose through LDS: T[col][row], chunk-XOR swizzle (chunk ^= col&7)
    unsigned short* T = S;                 // full 32 KB region, main loop done
#pragma unroll
    for (int mi = 0; mi < 4; ++mi)
#pragma unroll
      for (int ni = 0; ni < 4; ++ni) {
        int col  = wn + ni * 16 + lr;      // dk within tile, 0..127
        int rowb = wm + mi * 16 + lg * 4;  // l within tile, 4 consecutive rows
        ushort4 v4;
        v4.x = f2bf(acc[mi][ni][0]);
        v4.y = f2bf(acc[mi][ni][1]);
        v4.z = f2bf(acc[mi][ni][2]);
        v4.w = f2bf(acc[mi][ni][3]);
        int addr = col * 128 + (((rowb >> 3) ^ (col & 7)) * 8) + (rowb & 7);
        *(ushort4*)&T[addr] = v4;          // 8B aligned: (rowb&7) in {0,4}
      }
    __syncthreads();
    int bb = m0 >> 11;
    unsigned short* vdst = Vt + (((size_t)bb * ND + nc0) << 11) + (m0 & 2047);
#pragma unroll
    for (int pass = 0; pass < 8; ++pass) {
      int col = (tid >> 4) + pass * 16;    // 16 cols per pass
      int cc = tid & 15;                   // 16 chunks of 8 elems per col
      u32x4 val = *(const u32x4*)&T[col * 128 + ((cc ^ (col & 7)) * 8)];
      *(u32x4*)&vdst[((size_t)col << 11) + cc * 8] = val;  // 256B/16 lanes contiguous
    }
  } else {
#pragma unroll
    for (int mi = 0; mi < 4; ++mi)
#pragma unroll
      for (int ni = 0; ni < 4; ++ni)
#pragma unroll
        for (int r = 0; r < 4; ++r) {
          int row = m0 + wm + mi * 16 + lg * 4 + r;
          int col = nc0 + wn + ni * 16 + lr;
          unsigned short v = f2bf(acc[mi][ni][r]);
          if (z == 0) Qb[(size_t)row * ND + col] = v;
          else        Kb[(size_t)row * ND + col] = v;
        }
  }
}

// ---- out-proj GEMM: C[M,N] fp32 = A[M,K] bf16 * Bt[N,K]^T. 128x64 tile, BK=64.
__global__ __launch_bounds__(256) void k_gemm(const unsigned short* __restrict__ A,
                                              const unsigned short* __restrict__ Bt,
                                              float* __restrict__ Cout,
                                              int Msz, int Nsz, int Ksz) {
  __shared__ unsigned short As[8192];
  __shared__ unsigned short Bs[4096];
  int tid = threadIdx.x;
  int wave = tid >> 6, lane = tid & 63;
  int lr = lane & 15, lg = lane >> 4;
  int m0 = blockIdx.x * 128, n0 = blockIdx.y * 64;
  int wm = (wave >> 1) * 64, wn = (wave & 1) * 32;
  int srow = tid >> 3, spc = tid & 7;
  int sg = spc ^ (srow & 7);
  const unsigned short* Ag = A  + (size_t)(m0 + srow) * Ksz + sg * 8;
  const unsigned short* Bg = Bt + (size_t)(n0 + srow) * Ksz + sg * 8;
  f32x4 acc[4][2] = {};
  for (int t = 0; t < Ksz / 64; ++t) {
    int k0 = t * 64;
#pragma unroll
    for (int s = 0; s < 4; ++s)
      gl_lds16(Ag + (size_t)(s * 32) * Ksz + k0, &As[s * 2048 + tid * 8]);
#pragma unroll
    for (int s = 0; s < 2; ++s)
      gl_lds16(Bg + (size_t)(s * 32) * Ksz + k0, &Bs[s * 2048 + tid * 8]);
    __syncthreads();
#pragma unroll
    for (int ks = 0; ks < 2; ++ks) {
      bf16x8 af[4], bfr[2];
#pragma unroll
      for (int i = 0; i < 4; ++i) {
        int ar = wm + i * 16 + lr;
        af[i] = *(const bf16x8*)&As[ar * 64 + (((ks * 4 + lg) ^ (ar & 7)) * 8)];
      }
#pragma unroll
      for (int i = 0; i < 2; ++i) {
        int br = wn + i * 16 + lr;
        bfr[i] = *(const bf16x8*)&Bs[br * 64 + (((ks * 4 + lg) ^ (br & 7)) * 8)];
      }
#pragma unroll
      for (int mi = 0; mi < 4; ++mi)
#pragma unroll
        for (int ni = 0; ni < 2; ++ni)
          acc[mi][ni] = __builtin_amdgcn_mfma_f32_16x16x32_bf16(af[mi], bfr[ni], acc[mi][ni], 0, 0, 0);
    }
    __syncthreads();
  }
#pragma unroll
  for (int mi = 0; mi < 4; ++mi)
#pragma unroll
    for (int ni = 0; ni < 2; ++ni)
#pragma unroll
      for (int r = 0; r < 4; ++r) {
        int row = m0 + wm + mi * 16 + lg * 4 + r;
        int col = n0 + wn + ni * 16 + lr;
        Cout[(size_t)row * Nsz + col] = acc[mi][ni][r];
      }
}

// ---- fused flash attention (R10/R12 structure): swapped-QK^T (exp2), 3-buffer
// counted-vmcnt pipeline, far-tile zero-C bias fold, lane-local softmax common path.
__global__ __launch_bounds__(256, 3) void k_attn(const unsigned short* __restrict__ Qb,
                                                 const unsigned short* __restrict__ Kb,
                                                 const unsigned short* __restrict__ Vt,
                                                 const float* __restrict__ bias_tab,
                                                 const float* __restrict__ maskadd,
                                                 const int* __restrict__ maskall,
                                                 unsigned short* __restrict__ Ob) {
  __shared__ unsigned short Ks[3][4096];   // [64 phys keys][64 dk], XOR-swizzled chunks
  __shared__ unsigned short Vs[3][4096];   // [64 dk][64 keys natural], XOR-swizzled
  __shared__ float biasw[384];             // near band: biasw[d+191]
  int qt = blockIdx.x, bh = blockIdx.y;
  int b = bh / NH, h = bh % NH;
  int tid = threadIdx.x, wave = tid >> 6, lane = tid & 63;
  int lr = lane & 15, lg = lane >> 4;
  int q0 = qt * 64;
  for (int i = tid; i < 383; i += 256) biasw[i] = bias_tab[h * 4095 + 1856 + i];
  float cFlo = bias_tab[h * 4095];          // d <= -91 saturated (bucket 15)
  float cFhi = bias_tab[h * 4095 + 4094];   // d >= +91 saturated (bucket 31)
  const unsigned short* Kbase = Kb + (size_t)(b * NL) * ND + h * NDK;
  const unsigned short* Vbase = Vt + (size_t)(b * NH + h) * NDK * NL;
  int srow = tid >> 3, spc = tid & 7;
  int sg = spc ^ (srow & 7);
  // key permutation: phys row srow stores logical key l0; +32 phys -> l0+4
  int l0 = (srow >> 4) * 32 + ((srow >> 2) & 3) * 8 + (srow & 3);
  const unsigned short* Kg0 = Kbase + (size_t)l0 * ND + sg * 8;
  const unsigned short* Kg1 = Kbase + (size_t)(l0 + 4) * ND + sg * 8;
  const unsigned short* Vg0 = Vbase + (size_t)srow * NL + sg * 8;
  const unsigned short* Vg1 = Vbase + (size_t)(32 + srow) * NL + sg * 8;
  bf16x8 aq[2];
  int qw = q0 + wave * 16;
#pragma unroll
  for (int ks = 0; ks < 2; ++ks)
    aq[ks] = *(const bf16x8*)&Qb[(size_t)(b * NL + qw + lr) * ND + h * NDK + ks * 32 + lg * 8];
  const float* cbase = maskadd + b * NL;
  int nomask = __builtin_amdgcn_readfirstlane(maskall[b]);
  f32x4 accO[4] = {};
  float mst = -1e30f, lstl = 0.f;          // per-lane partial row-sum (16 keys/lane)
  int bconst = lg * 8 - wave * 16 - lr + 191 - q0;   // near idx = kt*64 + subk + bconst
  int src0 = (lane & 48) | ((lane >> 2) & 12);
  // prologue: stage tiles 0 and 1 into bufs 0, 1 (8 loads in flight)
  gl_lds16(Kg0, &Ks[0][tid * 8]);
  gl_lds16(Kg1, &Ks[0][2048 + tid * 8]);
  gl_lds16(Vg0, &Vs[0][tid * 8]);
  gl_lds16(Vg1, &Vs[0][2048 + tid * 8]);
  {
    size_t kok = (size_t)64 * ND, kov = 64;
    gl_lds16(Kg0 + kok, &Ks[1][tid * 8]);
    gl_lds16(Kg1 + kok, &Ks[1][2048 + tid * 8]);
    gl_lds16(Vg0 + kov, &Vs[1][tid * 8]);
    gl_lds16(Vg1 + kov, &Vs[1][2048 + tid * 8]);
  }
  asm volatile("s_waitcnt vmcnt(4) lgkmcnt(0)" ::: "memory");  // tile0 + biasw ready
  __builtin_amdgcn_s_barrier();
  int cur = 0;
  const int NT = NL / 64;
  for (int kt = 0; kt < NT; ++kt) {
    float4 cv[2][2];
    if (!nomask) {
#pragma unroll
      for (int hf = 0; hf < 2; ++hf)
#pragma unroll
        for (int qd = 0; qd < 2; ++qd)
          cv[hf][qd] = *(const float4*)&cbase[kt * 64 + hf * 32 + lg * 8 + qd * 4];
    }
    bool pf = (kt + 2 < NT);
    if (pf) {
      int st = cur + 2; if (st >= 3) st -= 3;
      size_t kok = (size_t)(kt + 2) * 64 * ND;
      size_t kov = (size_t)(kt + 2) * 64;
      gl_lds16(Kg0 + kok, &Ks[st][tid * 8]);
      gl_lds16(Kg1 + kok, &Ks[st][2048 + tid * 8]);
      gl_lds16(Vg0 + kov, &Vs[st][tid * 8]);
      gl_lds16(Vg1 + kov, &Vs[st][2048 + tid * 8]);
    }
    int kt64 = kt * 64;
    bool farlo = (kt64 + 63 < q0 - 90), farhi = (kt64 > q0 + 153);
    float ctile = farlo ? cFlo : (farhi ? cFhi : 0.0f);
    f32x4 s[4];
    __builtin_amdgcn_s_setprio(1);
    if (nomask && (farlo || farhi)) {
      // far tile, no mask: MFMA from zero C; ctile folded into softmax scalars
      const f32x4 z = {0.f, 0.f, 0.f, 0.f};
#pragma unroll
      for (int ni = 0; ni < 4; ++ni) {
        int kr = ni * 16 + lr;
        bf16x8 bk0 = *(const bf16x8*)&Ks[cur][kr * 64 + ((lg ^ (lr & 7)) * 8)];
        bf16x8 bk1 = *(const bf16x8*)&Ks[cur][kr * 64 + (((4 + lg) ^ (lr & 7)) * 8)];
        s[ni] = __builtin_amdgcn_mfma_f32_16x16x32_bf16(bk0, aq[0], z, 0, 0, 0);
        s[ni] = __builtin_amdgcn_mfma_f32_16x16x32_bf16(bk1, aq[1], s[ni], 0, 0, 0);
      }
    } else {
      if (farlo || farhi) {
#pragma unroll
        for (int ni = 0; ni < 4; ++ni)
#pragma unroll
          for (int r = 0; r < 4; ++r) s[ni][r] = 0.f;   // ctile folded later
      } else {
#pragma unroll
        for (int ni = 0; ni < 4; ++ni)
#pragma unroll
          for (int r = 0; r < 4; ++r)
            s[ni][r] = biasw[kt64 + (ni & 1) * 32 + (ni >> 1) * 4 + r + bconst];
      }
      if (!nomask) {
#pragma unroll
        for (int ni = 0; ni < 4; ++ni)
#pragma unroll
          for (int r = 0; r < 4; ++r)
            s[ni][r] += ((const float*)&cv[ni & 1][ni >> 1])[r];
      }
#pragma unroll
      for (int ni = 0; ni < 4; ++ni) {
        int kr = ni * 16 + lr;
        bf16x8 bk0 = *(const bf16x8*)&Ks[cur][kr * 64 + ((lg ^ (lr & 7)) * 8)];
        bf16x8 bk1 = *(const bf16x8*)&Ks[cur][kr * 64 + (((4 + lg) ^ (lr & 7)) * 8)];
        s[ni] = __builtin_amdgcn_mfma_f32_16x16x32_bf16(bk0, aq[0], s[ni], 0, 0, 0);
        s[ni] = __builtin_amdgcn_mfma_f32_16x16x32_bf16(bk1, aq[1], s[ni], 0, 0, 0);
      }
    }
    __builtin_amdgcn_s_setprio(0);
    // lane-local max over this lane's 16 keys (NO cross-lane on common path)
    f32x4 t0, t1;
#pragma unroll
    for (int r = 0; r < 4; ++r) t0[r] = fmaxf(s[0][r], s[1][r]);
#pragma unroll
    for (int r = 0; r < 4; ++r) t1[r] = fmaxf(s[2][r], s[3][r]);
#pragma unroll
    for (int r = 0; r < 4; ++r) t0[r] = fmaxf(t0[r], t1[r]);
    float lm = fmaxf(fmaxf(t0[0], t0[1]), fmaxf(t0[2], t0[3]));
    // defer-check: __all over lanes covers every row's max — equivalent condition
    if (!__all(lm + ctile - mst <= 8.0f)) {
      float pmax = fmaxf(lm, __shfl_xor(lm, 16));
      pmax = xmax32(pmax);
      float pm2 = pmax + ctile;
      float mnew = fmaxf(mst, pm2);
      float sc = fexp2(mst - mnew);
      float scB[4];
#pragma unroll
      for (int r = 0; r < 4; ++r) scB[r] = __shfl(sc, src0 | r);
#pragma unroll
      for (int ni = 0; ni < 4; ++ni)
#pragma unroll
        for (int r = 0; r < 4; ++r) accO[ni][r] *= scB[r];
      lstl *= sc;            // per-lane partial scales by its row's (uniform) sc
      mst = mnew;
    }
    float msub = mst - ctile;
#pragma unroll
    for (int ni = 0; ni < 4; ++ni)
#pragma unroll
      for (int r = 0; r < 4; ++r) s[ni][r] = fexp2(s[ni][r] - msub);
    // lane-local partial sum (cross-lane reduce deferred to epilogue)
    {
      f32x4 ta = s[0] + s[1];
      f32x4 tb = s[2] + s[3];
      ta = ta + tb;
      lstl += (ta[0] + ta[1]) + (ta[2] + ta[3]);
    }
    // pack P: lane's 16 values are exactly its PV A-fragments (key permutation)
    unsigned pw[8];
#pragma unroll
    for (int ni = 0; ni < 4; ++ni) {
      unsigned a, c;
      asm("v_cvt_pk_bf16_f32 %0, %1, %2" : "=v"(a) : "v"(s[ni][0]), "v"(s[ni][1]));
      asm("v_cvt_pk_bf16_f32 %0, %1, %2" : "=v"(c) : "v"(s[ni][2]), "v"(s[ni][3]));
      pw[ni * 2] = a; pw[ni * 2 + 1] = c;
    }
    u32x4 apw0 = {pw[0], pw[1], pw[4], pw[5]};
    u32x4 apw1 = {pw[2], pw[3], pw[6], pw[7]};
    bf16x8 ap0 = __builtin_bit_cast(bf16x8, apw0);
    bf16x8 ap1 = __builtin_bit_cast(bf16x8, apw1);
    // O += P @ V
    __builtin_amdgcn_s_setprio(1);
#pragma unroll
    for (int ni = 0; ni < 4; ++ni) {
      int vr = ni * 16 + lr;
      bf16x8 bv0 = *(const bf16x8*)&Vs[cur][vr * 64 + ((lg ^ (lr & 7)) * 8)];
      bf16x8 bv1 = *(const bf16x8*)&Vs[cur][vr * 64 + (((4 + lg) ^ (lr & 7)) * 8)];
      accO[ni] = __builtin_amdgcn_mfma_f32_16x16x32_bf16(ap0, bv0, accO[ni], 0, 0, 0);
      accO[ni] = __builtin_amdgcn_mfma_f32_16x16x32_bf16(ap1, bv1, accO[ni], 0, 0, 0);
    }
    __builtin_amdgcn_s_setprio(0);
    // counted wait: stage(t+1) complete, stage(t+2)'s 4 loads stay in flight
    if (pf) asm volatile("s_waitcnt vmcnt(4)" ::: "memory");
    else    asm volatile("s_waitcnt vmcnt(0)" ::: "memory");
    __builtin_amdgcn_s_barrier();
    cur = (cur == 2) ? 0 : cur + 1;
  }
  // epilogue: one cross-lane row-sum, then broadcast 1/l to accO's row layout
  float lst = lstl + __shfl_xor(lstl, 16);
  lst = xsum32(lst);
  float linv = 1.0f / lst;
  float lB[4];
#pragma unroll
  for (int r = 0; r < 4; ++r) lB[r] = __shfl(linv, src0 | r);
#pragma unroll
  for (int ni = 0; ni < 4; ++ni)
#pragma unroll
    for (int r = 0; r < 4; ++r) {
      int qg = qw + lg * 4 + r;
      int col = h * NDK + ni * 16 + lr;
      Ob[(size_t)(b * NL + qg) * ND + col] = f2bf(accO[ni][r] * lB[r]);
    }
}

extern "C" void kernel_launch(void* const* d_in, const int* in_sizes, int n_in,
                              void* d_out, int out_size, void* d_ws, size_t ws_size,
                              hipStream_t stream) {
  const float* query  = (const float*)d_in[0];
  const float* keyval = (const float*)d_in[1];
  const int*   mask   = (const int*)d_in[2];
  const float* Wq     = (const float*)d_in[3];
  const float* Wk     = (const float*)d_in[4];
  const float* Wv     = (const float*)d_in[5];
  const float* Wo     = (const float*)d_in[6];
  const float* rel    = (const float*)d_in[7];

  char* ws = (char*)d_ws;
  unsigned short* q_bf  = (unsigned short*)(ws);              // 4096x768 bf16
  unsigned short* kv_bf = (unsigned short*)(ws + 6291456);
  unsigned short* Wq_t  = (unsigned short*)(ws + 12582912);   // [N][K] bf16 (x 0.125*log2e)
  unsigned short* Wk_t  = (unsigned short*)(ws + 13762560);
  unsigned short* Wv_t  = (unsigned short*)(ws + 14942208);
  unsigned short* Wo_t  = (unsigned short*)(ws + 16121856);
  unsigned short* Qb    = (unsigned short*)(ws + 17301504);   // [B,L,H,DK]
  unsigned short* Kb    = (unsigned short*)(ws + 23592960);
  unsigned short* Vt    = (unsigned short*)(ws + 29884416);   // [B,768,L]
  unsigned short* Ob    = (unsigned short*)(ws + 36175872);   // [B,L,H*DK]
  float* bias_tab       = (float*)(ws + 42467328);            // [H][4095], x log2e
  float* maskadd        = (float*)(ws + 42663936);            // [B][L]
  int*   maskall        = (int*)(ws + 42680320);              // [B]

  k_prep<<<dim3(8642), dim3(256), 0, stream>>>(query, keyval, Wq, Wk, Wv, Wo, rel, mask,
                                               q_bf, kv_bf, Wq_t, Wk_t, Wv_t, Wo_t,
                                               bias_tab, maskadd, maskall);
  k_gemm_qkv<<<dim3(32, 18), dim3(256), 0, stream>>>(q_bf, kv_bf, Wq_t, Qb, Kb, Vt);
  k_attn<<<dim3(32, 24), dim3(256), 0, stream>>>(Qb, Kb, Vt, bias_tab, maskadd, maskall, Ob);
  k_gemm<<<dim3(32, 12), dim3(256), 0, stream>>>(Ob, Wo_t, (float*)d_out, NM, ND, ND);
}

// Round 14
// 97.295 us; speedup vs baseline: 1.2076x; 1.0859x over previous
//
#include <hip/hip_runtime.h>
#include <stdint.h>

typedef __attribute__((ext_vector_type(8))) short bf16x8;
typedef __attribute__((ext_vector_type(4))) float f32x4;
typedef __attribute__((ext_vector_type(4))) unsigned int u32x4;

#define NB 2
#define NL 2048
#define ND 768
#define NH 12
#define NDK 64
#define NM 4096   // NB*NL
#define LOG2E 1.4426950408889634f

template<int N> struct IC { static constexpr int v = N; };

__device__ __forceinline__ unsigned short f2bf(float f) {
  unsigned u = __builtin_bit_cast(unsigned, f);
  u += 0x7FFFu + ((u >> 16) & 1u);          // RNE
  return (unsigned short)(u >> 16);
}

__device__ __forceinline__ float fexp2(float x) {
  float r;
  asm("v_exp_f32 %0, %1" : "=v"(r) : "v"(x));
  return r;
}

__device__ __forceinline__ float xmax32(float x) { return fmaxf(x, __shfl_xor(x, 32)); }
__device__ __forceinline__ float xsum32(float x) { return x + __shfl_xor(x, 32); }

__device__ __forceinline__ void gl_lds16(const unsigned short* g, unsigned short* l) {
  __builtin_amdgcn_global_load_lds((const __attribute__((address_space(1))) void*)g,
                                   (__attribute__((address_space(3))) void*)l, 16, 0, 0);
}

// ---- merged prep: conv (0..6143) | wt (6144..8447) | bias (8448..8639) | maskadd (8640..8641)
__global__ __launch_bounds__(256) void k_prep(const float* __restrict__ query,
                                              const float* __restrict__ keyval,
                                              const float* __restrict__ Wq,
                                              const float* __restrict__ Wk,
                                              const float* __restrict__ Wv,
                                              const float* __restrict__ Wo,
                                              const float* __restrict__ rel_emb,
                                              const int* __restrict__ mask,
                                              unsigned short* __restrict__ q_bf,
                                              unsigned short* __restrict__ kv_bf,
                                              unsigned short* __restrict__ Wq_t,
                                              unsigned short* __restrict__ Wk_t,
                                              unsigned short* __restrict__ Wv_t,
                                              unsigned short* __restrict__ Wo_t,
                                              float* __restrict__ bias_tab,
                                              float* __restrict__ maskadd,
                                              int* __restrict__ maskall) {
  __shared__ float shbuf[32 * 33];
  int blk = blockIdx.x, tid = threadIdx.x;
  if (blk < 6144) {
    int y = blk / 3072;
    int i = (blk - y * 3072) * 256 + tid;
    const float* src = y ? keyval : query;
    unsigned short* dst = y ? kv_bf : q_bf;
    float4 v = ((const float4*)src)[i];
    ushort4 o;
    o.x = f2bf(v.x); o.y = f2bf(v.y); o.z = f2bf(v.z); o.w = f2bf(v.w);
    ((ushort4*)dst)[i] = o;
  } else if (blk < 8448) {
    int rel = blk - 6144;
    int z = rel / 576, r2 = rel - z * 576;
    int bx = (r2 % 24) * 32, by = (r2 / 24) * 32;
    const float* w = (z == 0) ? Wq : (z == 1) ? Wk : (z == 2) ? Wv : Wo;
    unsigned short* o = (z == 0) ? Wq_t : (z == 1) ? Wk_t : (z == 2) ? Wv_t : Wo_t;
    float scale = (z == 0) ? 0.125f * LOG2E : 1.0f;
    int tx = tid & 31, ty = tid >> 5;
    float (*t)[33] = (float(*)[33])shbuf;
    for (int r = 0; r < 32; r += 8)
      t[ty + r][tx] = w[(by + ty + r) * ND + bx + tx];
    __syncthreads();
    for (int r = 0; r < 32; r += 8)
      o[(bx + ty + r) * ND + by + tx] = f2bf(t[tx][ty + r] * scale);
  } else if (blk < 8640) {
    int idx = (blk - 8448) * 256 + tid;
    if (idx >= 4095 * NH) return;
    int h = idx % NH;
    int di = idx / NH;
    int rel = di - 2047;          // rel = k - q
    int n = -rel;
    int ret = 0;
    if (n < 0) { ret = 16; n = -n; }
    int b;
    if (n < 8) {
      b = ret + n;
    } else {
      int v = (n >= 91) ? 7 : (n >= 64) ? 6 : (n >= 46) ? 5 : (n >= 32) ? 4
            : (n >= 23) ? 3 : (n >= 16) ? 2 : (n >= 12) ? 1 : 0;
      b = ret + 8 + v;
    }
    bias_tab[h * 4095 + di] = rel_emb[b * NH + h] * LOG2E;
  } else {
    int b = blk - 8640;
    int* red = (int*)shbuf;
    int acc = 1;
    for (int i = tid; i < NL; i += 256) {
      int m = mask[b * NL + i];
      maskadd[b * NL + i] = m ? 0.0f : -1e30f;
      acc &= (m != 0) ? 1 : 0;
    }
    red[tid] = acc;
    __syncthreads();
    for (int s2 = 128; s2 > 0; s2 >>= 1) {
      if (tid < s2) red[tid] &= red[tid + s2];
      __syncthreads();
    }
    if (tid == 0) maskall[b] = red[0];
  }
}

// ---- fused QKV GEMM, 128x96 tile: grid (32, 24) = 768 blocks = exactly 3/CU.
// y/8 = {Q,K,V}; nc0 = (y%8)*96. Wave-tile 64x48 (acc[4][3]). V blocks transpose
// through LDS for 256B-coalesced Vt stores.
__global__ __launch_bounds__(256) void k_gemm_qkv(const unsigned short* __restrict__ q_bf,
                                                  const unsigned short* __restrict__ kv_bf,
                                                  const unsigned short* __restrict__ Wt,
                                                  unsigned short* __restrict__ Qb,
                                                  unsigned short* __restrict__ Kb,
                                                  unsigned short* __restrict__ Vt) {
  __shared__ unsigned short S[14336];   // A: [0,8192) 16KB, B: [8192,14336) 12KB
  unsigned short* As = S;
  unsigned short* Bs = S + 8192;
  int tid = threadIdx.x;
  int wave = tid >> 6, lane = tid & 63;
  int lr = lane & 15, lg = lane >> 4;
  int m0 = blockIdx.x * 128;
  int z = blockIdx.y >> 3;                 // 0=Q, 1=K, 2=V
  int nc0 = (blockIdx.y & 7) * 96;         // col within the 768-wide section
  const unsigned short* A  = (z == 0) ? q_bf : kv_bf;
  const unsigned short* Bt = Wt + (size_t)blockIdx.y * 96 * ND;
  int wm = (wave >> 1) * 64, wn = (wave & 1) * 48;
  int srow = tid >> 3, spc = tid & 7;
  int sg = spc ^ (srow & 7);
  const unsigned short* Ag = A  + (size_t)(m0 + srow) * ND + sg * 8;
  const unsigned short* Bg = Bt + (size_t)srow * ND + sg * 8;
  f32x4 acc[4][3] = {};
  for (int t = 0; t < ND / 64; ++t) {
    int k0 = t * 64;
#pragma unroll
    for (int s = 0; s < 4; ++s)
      gl_lds16(Ag + (size_t)(s * 32) * ND + k0, &As[s * 2048 + tid * 8]);
#pragma unroll
    for (int s = 0; s < 3; ++s)
      gl_lds16(Bg + (size_t)(s * 32) * ND + k0, &Bs[s * 2048 + tid * 8]);
    __syncthreads();
#pragma unroll
    for (int ks = 0; ks < 2; ++ks) {
      bf16x8 af[4], bfr[3];
#pragma unroll
      for (int i = 0; i < 4; ++i) {
        int ar = wm + i * 16 + lr;
        af[i] = *(const bf16x8*)&As[ar * 64 + (((ks * 4 + lg) ^ (ar & 7)) * 8)];
      }
#pragma unroll
      for (int i = 0; i < 3; ++i) {
        int br = wn + i * 16 + lr;
        bfr[i] = *(const bf16x8*)&Bs[br * 64 + (((ks * 4 + lg) ^ (br & 7)) * 8)];
      }
#pragma unroll
      for (int mi = 0; mi < 4; ++mi)
#pragma unroll
        for (int ni = 0; ni < 3; ++ni)
          acc[mi][ni] = __builtin_amdgcn_mfma_f32_16x16x32_bf16(af[mi], bfr[ni], acc[mi][ni], 0, 0, 0);
    }
    __syncthreads();
  }
  if (z == 2) {
    // transpose through LDS: T[col][row], chunk-XOR swizzle (chunk ^= col&7)
    unsigned short* T = S;                 // 96*128 shorts = 24KB <= 28KB region
#pragma unroll
    for (int mi = 0; mi < 4; ++mi)
#pragma unroll
      for (int ni = 0; ni < 3; ++ni) {
        int col  = wn + ni * 16 + lr;      // dk within tile, 0..95
        int rowb = wm + mi * 16 + lg * 4;  // l within tile, 4 consecutive rows
        ushort4 v4;
        v4.x = f2bf(acc[mi][ni][0]);
        v4.y = f2bf(acc[mi][ni][1]);
        v4.z = f2bf(acc[mi][ni][2]);
        v4.w = f2bf(acc[mi][ni][3]);
        int addr = col * 128 + (((rowb >> 3) ^ (col & 7)) * 8) + (rowb & 7);
        *(ushort4*)&T[addr] = v4;          // 8B aligned: (rowb&7) in {0,4}
      }
    __syncthreads();
    int bb = m0 >> 11;
    unsigned short* vdst = Vt + (((size_t)bb * ND + nc0) << 11) + (m0 & 2047);
#pragma unroll
    for (int pass = 0; pass < 6; ++pass) {
      int col = (tid >> 4) + pass * 16;    // 16 cols per pass, 96 total
      int cc = tid & 15;                   // 16 chunks of 8 elems per col
      u32x4 val = *(const u32x4*)&T[col * 128 + ((cc ^ (col & 7)) * 8)];
      *(u32x4*)&vdst[((size_t)col << 11) + cc * 8] = val;  // 256B/16 lanes contiguous
    }
  } else {
#pragma unroll
    for (int mi = 0; mi < 4; ++mi)
#pragma unroll
      for (int ni = 0; ni < 3; ++ni)
#pragma unroll
        for (int r = 0; r < 4; ++r) {
          int row = m0 + wm + mi * 16 + lg * 4 + r;
          int col = nc0 + wn + ni * 16 + lr;
          unsigned short v = f2bf(acc[mi][ni][r]);
          if (z == 0) Qb[(size_t)row * ND + col] = v;
          else        Kb[(size_t)row * ND + col] = v;
        }
  }
}

// ---- out-proj GEMM: C[M,N] fp32 = A[M,K] bf16 * Bt[N,K]^T. 128x64 tile, BK=64.
__global__ __launch_bounds__(256) void k_gemm(const unsigned short* __restrict__ A,
                                              const unsigned short* __restrict__ Bt,
                                              float* __restrict__ Cout,
                                              int Msz, int Nsz, int Ksz) {
  __shared__ unsigned short As[8192];
  __shared__ unsigned short Bs[4096];
  int tid = threadIdx.x;
  int wave = tid >> 6, lane = tid & 63;
  int lr = lane & 15, lg = lane >> 4;
  int m0 = blockIdx.x * 128, n0 = blockIdx.y * 64;
  int wm = (wave >> 1) * 64, wn = (wave & 1) * 32;
  int srow = tid >> 3, spc = tid & 7;
  int sg = spc ^ (srow & 7);
  const unsigned short* Ag = A  + (size_t)(m0 + srow) * Ksz + sg * 8;
  const unsigned short* Bg = Bt + (size_t)(n0 + srow) * Ksz + sg * 8;
  f32x4 acc[4][2] = {};
  for (int t = 0; t < Ksz / 64; ++t) {
    int k0 = t * 64;
#pragma unroll
    for (int s = 0; s < 4; ++s)
      gl_lds16(Ag + (size_t)(s * 32) * Ksz + k0, &As[s * 2048 + tid * 8]);
#pragma unroll
    for (int s = 0; s < 2; ++s)
      gl_lds16(Bg + (size_t)(s * 32) * Ksz + k0, &Bs[s * 2048 + tid * 8]);
    __syncthreads();
#pragma unroll
    for (int ks = 0; ks < 2; ++ks) {
      bf16x8 af[4], bfr[2];
#pragma unroll
      for (int i = 0; i < 4; ++i) {
        int ar = wm + i * 16 + lr;
        af[i] = *(const bf16x8*)&As[ar * 64 + (((ks * 4 + lg) ^ (ar & 7)) * 8)];
      }
#pragma unroll
      for (int i = 0; i < 2; ++i) {
        int br = wn + i * 16 + lr;
        bfr[i] = *(const bf16x8*)&Bs[br * 64 + (((ks * 4 + lg) ^ (br & 7)) * 8)];
      }
#pragma unroll
      for (int mi = 0; mi < 4; ++mi)
#pragma unroll
        for (int ni = 0; ni < 2; ++ni)
          acc[mi][ni] = __builtin_amdgcn_mfma_f32_16x16x32_bf16(af[mi], bfr[ni], acc[mi][ni], 0, 0, 0);
    }
    __syncthreads();
  }
#pragma unroll
  for (int mi = 0; mi < 4; ++mi)
#pragma unroll
    for (int ni = 0; ni < 2; ++ni)
#pragma unroll
      for (int r = 0; r < 4; ++r) {
        int row = m0 + wm + mi * 16 + lg * 4 + r;
        int col = n0 + wn + ni * 16 + lr;
        Cout[(size_t)row * Nsz + col] = acc[mi][ni][r];
      }
}

// ---- fused flash attention (R12 structure) with compile-time-unrolled buffer
// cycle: body<CUR,PF> makes all LDS addresses loop-invariant (base + immediate),
// deleting per-iter buffer-index arithmetic. Stage pointers advance by constants.
__global__ __launch_bounds__(256, 3) void k_attn(const unsigned short* __restrict__ Qb,
                                                 const unsigned short* __restrict__ Kb,
                                                 const unsigned short* __restrict__ Vt,
                                                 const float* __restrict__ bias_tab,
                                                 const float* __restrict__ maskadd,
                                                 const int* __restrict__ maskall,
                                                 unsigned short* __restrict__ Ob) {
  __shared__ unsigned short Ks[3][4096];   // [64 phys keys][64 dk], XOR-swizzled chunks
  __shared__ unsigned short Vs[3][4096];   // [64 dk][64 keys natural], XOR-swizzled
  __shared__ float biasw[384];             // near band: biasw[d+191]
  int qt = blockIdx.x, bh = blockIdx.y;
  int b = bh / NH, h = bh % NH;
  int tid = threadIdx.x, wave = tid >> 6, lane = tid & 63;
  int lr = lane & 15, lg = lane >> 4;
  int q0 = qt * 64;
  for (int i = tid; i < 383; i += 256) biasw[i] = bias_tab[h * 4095 + 1856 + i];
  float cFlo = bias_tab[h * 4095];          // d <= -91 saturated (bucket 15)
  float cFhi = bias_tab[h * 4095 + 4094];   // d >= +91 saturated (bucket 31)
  const unsigned short* Kbase = Kb + (size_t)(b * NL) * ND + h * NDK;
  const unsigned short* Vbase = Vt + (size_t)(b * NH + h) * NDK * NL;
  int srow = tid >> 3, spc = tid & 7;
  int sg = spc ^ (srow & 7);
  // key permutation: phys row srow stores logical key l0; +32 phys -> l0+4
  int l0 = (srow >> 4) * 32 + ((srow >> 2) & 3) * 8 + (srow & 3);
  const unsigned short* Kg0 = Kbase + (size_t)l0 * ND + sg * 8;
  const unsigned short* Kg1 = Kbase + (size_t)(l0 + 4) * ND + sg * 8;
  const unsigned short* Vg0 = Vbase + (size_t)srow * NL + sg * 8;
  const unsigned short* Vg1 = Vbase + (size_t)(32 + srow) * NL + sg * 8;
  bf16x8 aq[2];
  int qw = q0 + wave * 16;
#pragma unroll
  for (int ks = 0; ks < 2; ++ks)
    aq[ks] = *(const bf16x8*)&Qb[(size_t)(b * NL + qw + lr) * ND + h * NDK + ks * 32 + lg * 8];
  const float* cbase = maskadd + b * NL;
  int nomask = __builtin_amdgcn_readfirstlane(maskall[b]);
  f32x4 accO[4] = {};
  float mst = -1e30f, lstl = 0.f;          // per-lane partial row-sum (16 keys/lane)
  int bconst = lg * 8 - wave * 16 - lr + 191 - q0;
  int src0 = (lane & 48) | ((lane >> 2) & 12);
  // prologue: stage tiles 0 and 1 into bufs 0, 1 (8 loads in flight)
  gl_lds16(Kg0, &Ks[0][tid * 8]);
  gl_lds16(Kg1, &Ks[0][2048 + tid * 8]);
  gl_lds16(Vg0, &Vs[0][tid * 8]);
  gl_lds16(Vg1, &Vs[0][2048 + tid * 8]);
  {
    size_t kok = (size_t)64 * ND, kov = 64;
    gl_lds16(Kg0 + kok, &Ks[1][tid * 8]);
    gl_lds16(Kg1 + kok, &Ks[1][2048 + tid * 8]);
    gl_lds16(Vg0 + kov, &Vs[1][tid * 8]);
    gl_lds16(Vg1 + kov, &Vs[1][2048 + tid * 8]);
  }
  asm volatile("s_waitcnt vmcnt(4) lgkmcnt(0)" ::: "memory");  // tile0 + biasw ready
  __builtin_amdgcn_s_barrier();
  // stage pointers for tile 2 onward (advance by constant stride per stage)
  const unsigned short* sk0 = Kg0 + (size_t)2 * 64 * ND;
  const unsigned short* sk1 = Kg1 + (size_t)2 * 64 * ND;
  const unsigned short* sv0 = Vg0 + 2 * 64;
  const unsigned short* sv1 = Vg1 + 2 * 64;

  auto body = [&](int kt_, auto CURc, auto PFc) {
    constexpr int CUR = decltype(CURc)::v;
    constexpr int PF  = decltype(PFc)::v;
    constexpr int ST  = (CUR + 2) % 3;
    float4 cv[2][2];
    if (!nomask) {
#pragma unroll
      for (int hf = 0; hf < 2; ++hf)
#pragma unroll
        for (int qd = 0; qd < 2; ++qd)
          cv[hf][qd] = *(const float4*)&cbase[kt_ * 64 + hf * 32 + lg * 8 + qd * 4];
    }
    if (PF) {
      gl_lds16(sk0, &Ks[ST][tid * 8]);
      gl_lds16(sk1, &Ks[ST][2048 + tid * 8]);
      gl_lds16(sv0, &Vs[ST][tid * 8]);
      gl_lds16(sv1, &Vs[ST][2048 + tid * 8]);
      sk0 += 64 * ND; sk1 += 64 * ND; sv0 += 64; sv1 += 64;
    }
    int kt64 = kt_ * 64;
    bool farlo = (kt64 + 63 < q0 - 90), farhi = (kt64 > q0 + 153);
    float ctile = farlo ? cFlo : (farhi ? cFhi : 0.0f);
    f32x4 s[4];
    __builtin_amdgcn_s_setprio(1);
    if (nomask && (farlo || farhi)) {
      const f32x4 z = {0.f, 0.f, 0.f, 0.f};
#pragma unroll
      for (int ni = 0; ni < 4; ++ni) {
        int kr = ni * 16 + lr;
        bf16x8 bk0 = *(const bf16x8*)&Ks[CUR][kr * 64 + ((lg ^ (lr & 7)) * 8)];
        bf16x8 bk1 = *(const bf16x8*)&Ks[CUR][kr * 64 + (((4 + lg) ^ (lr & 7)) * 8)];
        s[ni] = __builtin_amdgcn_mfma_f32_16x16x32_bf16(bk0, aq[0], z, 0, 0, 0);
        s[ni] = __builtin_amdgcn_mfma_f32_16x16x32_bf16(bk1, aq[1], s[ni], 0, 0, 0);
      }
    } else {
      if (farlo || farhi) {
#pragma unroll
        for (int ni = 0; ni < 4; ++ni)
#pragma unroll
          for (int r = 0; r < 4; ++r) s[ni][r] = 0.f;   // ctile folded later
      } else {
#pragma unroll
        for (int ni = 0; ni < 4; ++ni)
#pragma unroll
          for (int r = 0; r < 4; ++r)
            s[ni][r] = biasw[kt64 + (ni & 1) * 32 + (ni >> 1) * 4 + r + bconst];
      }
      if (!nomask) {
#pragma unroll
        for (int ni = 0; ni < 4; ++ni)
#pragma unroll
          for (int r = 0; r < 4; ++r)
            s[ni][r] += ((const float*)&cv[ni & 1][ni >> 1])[r];
      }
#pragma unroll
      for (int ni = 0; ni < 4; ++ni) {
        int kr = ni * 16 + lr;
        bf16x8 bk0 = *(const bf16x8*)&Ks[CUR][kr * 64 + ((lg ^ (lr & 7)) * 8)];
        bf16x8 bk1 = *(const bf16x8*)&Ks[CUR][kr * 64 + (((4 + lg) ^ (lr & 7)) * 8)];
        s[ni] = __builtin_amdgcn_mfma_f32_16x16x32_bf16(bk0, aq[0], s[ni], 0, 0, 0);
        s[ni] = __builtin_amdgcn_mfma_f32_16x16x32_bf16(bk1, aq[1], s[ni], 0, 0, 0);
      }
    }
    __builtin_amdgcn_s_setprio(0);
    // lane-local max over this lane's 16 keys (no cross-lane on common path)
    f32x4 t0, t1;
#pragma unroll
    for (int r = 0; r < 4; ++r) t0[r] = fmaxf(s[0][r], s[1][r]);
#pragma unroll
    for (int r = 0; r < 4; ++r) t1[r] = fmaxf(s[2][r], s[3][r]);
#pragma unroll
    for (int r = 0; r < 4; ++r) t0[r] = fmaxf(t0[r], t1[r]);
    float lm = fmaxf(fmaxf(t0[0], t0[1]), fmaxf(t0[2], t0[3]));
    if (!__all(lm + ctile - mst <= 8.0f)) {
      float pmax = fmaxf(lm, __shfl_xor(lm, 16));
      pmax = xmax32(pmax);
      float pm2 = pmax + ctile;
      float mnew = fmaxf(mst, pm2);
      float sc = fexp2(mst - mnew);
      float scB[4];
#pragma unroll
      for (int r = 0; r < 4; ++r) scB[r] = __shfl(sc, src0 | r);
#pragma unroll
      for (int ni = 0; ni < 4; ++ni)
#pragma unroll
        for (int r = 0; r < 4; ++r) accO[ni][r] *= scB[r];
      lstl *= sc;
      mst = mnew;
    }
    float msub = mst - ctile;
#pragma unroll
    for (int ni = 0; ni < 4; ++ni)
#pragma unroll
      for (int r = 0; r < 4; ++r) s[ni][r] = fexp2(s[ni][r] - msub);
    {
      f32x4 ta = s[0] + s[1];
      f32x4 tb = s[2] + s[3];
      ta = ta + tb;
      lstl += (ta[0] + ta[1]) + (ta[2] + ta[3]);
    }
    // pack P: lane's 16 values are exactly its PV A-fragments (key permutation)
    unsigned pw[8];
#pragma unroll
    for (int ni = 0; ni < 4; ++ni) {
      unsigned a, c;
      asm("v_cvt_pk_bf16_f32 %0, %1, %2" : "=v"(a) : "v"(s[ni][0]), "v"(s[ni][1]));
      asm("v_cvt_pk_bf16_f32 %0, %1, %2" : "=v"(c) : "v"(s[ni][2]), "v"(s[ni][3]));
      pw[ni * 2] = a; pw[ni * 2 + 1] = c;
    }
    u32x4 apw0 = {pw[0], pw[1], pw[4], pw[5]};
    u32x4 apw1 = {pw[2], pw[3], pw[6], pw[7]};
    bf16x8 ap0 = __builtin_bit_cast(bf16x8, apw0);
    bf16x8 ap1 = __builtin_bit_cast(bf16x8, apw1);
    // O += P @ V
    __builtin_amdgcn_s_setprio(1);
#pragma unroll
    for (int ni = 0; ni < 4; ++ni) {
      int vr = ni * 16 + lr;
      bf16x8 bv0 = *(const bf16x8*)&Vs[CUR][vr * 64 + ((lg ^ (lr & 7)) * 8)];
      bf16x8 bv1 = *(const bf16x8*)&Vs[CUR][vr * 64 + (((4 + lg) ^ (lr & 7)) * 8)];
      accO[ni] = __builtin_amdgcn_mfma_f32_16x16x32_bf16(ap0, bv0, accO[ni], 0, 0, 0);
      accO[ni] = __builtin_amdgcn_mfma_f32_16x16x32_bf16(ap1, bv1, accO[ni], 0, 0, 0);
    }
    __builtin_amdgcn_s_setprio(0);
    if (PF) asm volatile("s_waitcnt vmcnt(4)" ::: "memory");
    else    asm volatile("s_waitcnt vmcnt(0)" ::: "memory");
    __builtin_amdgcn_s_barrier();
  };

  for (int kt = 0; kt < 30; kt += 3) {   // tile kt uses buf kt%3; stages kt+2
    body(kt,     IC<0>{}, IC<1>{});
    body(kt + 1, IC<1>{}, IC<1>{});
    body(kt + 2, IC<2>{}, IC<1>{});
  }
  body(30, IC<0>{}, IC<0>{});
  body(31, IC<1>{}, IC<0>{});

  // epilogue: one cross-lane row-sum, then broadcast 1/l to accO's row layout
  float lst = lstl + __shfl_xor(lstl, 16);
  lst = xsum32(lst);
  float linv = 1.0f / lst;
  float lB[4];
#pragma unroll
  for (int r = 0; r < 4; ++r) lB[r] = __shfl(linv, src0 | r);
#pragma unroll
  for (int ni = 0; ni < 4; ++ni)
#pragma unroll
    for (int r = 0; r < 4; ++r) {
      int qg = qw + lg * 4 + r;
      int col = h * NDK + ni * 16 + lr;
      Ob[(size_t)(b * NL + qg) * ND + col] = f2bf(accO[ni][r] * lB[r]);
    }
}

extern "C" void kernel_launch(void* const* d_in, const int* in_sizes, int n_in,
                              void* d_out, int out_size, void* d_ws, size_t ws_size,
                              hipStream_t stream) {
  const float* query  = (const float*)d_in[0];
  const float* keyval = (const float*)d_in[1];
  const int*   mask   = (const int*)d_in[2];
  const float* Wq     = (const float*)d_in[3];
  const float* Wk     = (const float*)d_in[4];
  const float* Wv     = (const float*)d_in[5];
  const float* Wo     = (const float*)d_in[6];
  const float* rel    = (const float*)d_in[7];

  char* ws = (char*)d_ws;
  unsigned short* q_bf  = (unsigned short*)(ws);              // 4096x768 bf16
  unsigned short* kv_bf = (unsigned short*)(ws + 6291456);
  unsigned short* Wq_t  = (unsigned short*)(ws + 12582912);   // [N][K] bf16 (x 0.125*log2e)
  unsigned short* Wk_t  = (unsigned short*)(ws + 13762560);
  unsigned short* Wv_t  = (unsigned short*)(ws + 14942208);
  unsigned short* Wo_t  = (unsigned short*)(ws + 16121856);
  unsigned short* Qb    = (unsigned short*)(ws + 17301504);   // [B,L,H,DK]
  unsigned short* Kb    = (unsigned short*)(ws + 23592960);
  unsigned short* Vt    = (unsigned short*)(ws + 29884416);   // [B,768,L]
  unsigned short* Ob    = (unsigned short*)(ws + 36175872);   // [B,L,H*DK]
  float* bias_tab       = (float*)(ws + 42467328);            // [H][4095], x log2e
  float* maskadd        = (float*)(ws + 42663936);            // [B][L]
  int*   maskall        = (int*)(ws + 42680320);              // [B]

  k_prep<<<dim3(8642), dim3(256), 0, stream>>>(query, keyval, Wq, Wk, Wv, Wo, rel, mask,
                                               q_bf, kv_bf, Wq_t, Wk_t, Wv_t, Wo_t,
                                               bias_tab, maskadd, maskall);
  k_gemm_qkv<<<dim3(32, 24), dim3(256), 0, stream>>>(q_bf, kv_bf, Wq_t, Qb, Kb, Vt);
  k_attn<<<dim3(32, 24), dim3(256), 0, stream>>>(Qb, Kb, Vt, bias_tab, maskadd, maskall, Ob);
  k_gemm<<<dim3(32, 12), dim3(256), 0, stream>>>(Ob, Wo_t, (float*)d_out, NM, ND, ND);
}

// Round 15
// 93.308 us; speedup vs baseline: 1.2592x; 1.0427x over previous
//
#include <hip/hip_runtime.h>
#include <stdint.h>

typedef __attribute__((ext_vector_type(8))) short bf16x8;
typedef __attribute__((ext_vector_type(4))) float f32x4;
typedef __attribute__((ext_vector_type(4))) unsigned int u32x4;

#define NB 2
#define NL 2048
#define ND 768
#define NH 12
#define NDK 64
#define NM 4096   // NB*NL
#define LOG2E 1.4426950408889634f

template<int N> struct IC { static constexpr int v = N; };

__device__ __forceinline__ unsigned short f2bf(float f) {
  unsigned u = __builtin_bit_cast(unsigned, f);
  u += 0x7FFFu + ((u >> 16) & 1u);          // RNE
  return (unsigned short)(u >> 16);
}

__device__ __forceinline__ float fexp2(float x) {
  float r;
  asm("v_exp_f32 %0, %1" : "=v"(r) : "v"(x));
  return r;
}

__device__ __forceinline__ float xmax32(float x) { return fmaxf(x, __shfl_xor(x, 32)); }
__device__ __forceinline__ float xsum32(float x) { return x + __shfl_xor(x, 32); }

__device__ __forceinline__ void gl_lds16(const unsigned short* g, unsigned short* l) {
  __builtin_amdgcn_global_load_lds((const __attribute__((address_space(1))) void*)g,
                                   (__attribute__((address_space(3))) void*)l, 16, 0, 0);
}

// ---- merged prep: conv (0..6143) | wt (6144..8447) | bias (8448..8639) | maskadd (8640..8641)
__global__ __launch_bounds__(256) void k_prep(const float* __restrict__ query,
                                              const float* __restrict__ keyval,
                                              const float* __restrict__ Wq,
                                              const float* __restrict__ Wk,
                                              const float* __restrict__ Wv,
                                              const float* __restrict__ Wo,
                                              const float* __restrict__ rel_emb,
                                              const int* __restrict__ mask,
                                              unsigned short* __restrict__ q_bf,
                                              unsigned short* __restrict__ kv_bf,
                                              unsigned short* __restrict__ Wq_t,
                                              unsigned short* __restrict__ Wk_t,
                                              unsigned short* __restrict__ Wv_t,
                                              unsigned short* __restrict__ Wo_t,
                                              float* __restrict__ bias_tab,
                                              float* __restrict__ maskadd,
                                              int* __restrict__ maskall) {
  __shared__ float shbuf[32 * 33];
  int blk = blockIdx.x, tid = threadIdx.x;
  if (blk < 6144) {
    int y = blk / 3072;
    int i = (blk - y * 3072) * 256 + tid;
    const float* src = y ? keyval : query;
    unsigned short* dst = y ? kv_bf : q_bf;
    float4 v = ((const float4*)src)[i];
    ushort4 o;
    o.x = f2bf(v.x); o.y = f2bf(v.y); o.z = f2bf(v.z); o.w = f2bf(v.w);
    ((ushort4*)dst)[i] = o;
  } else if (blk < 8448) {
    int rel = blk - 6144;
    int z = rel / 576, r2 = rel - z * 576;
    int bx = (r2 % 24) * 32, by = (r2 / 24) * 32;
    const float* w = (z == 0) ? Wq : (z == 1) ? Wk : (z == 2) ? Wv : Wo;
    unsigned short* o = (z == 0) ? Wq_t : (z == 1) ? Wk_t : (z == 2) ? Wv_t : Wo_t;
    float scale = (z == 0) ? 0.125f * LOG2E : 1.0f;
    int tx = tid & 31, ty = tid >> 5;
    float (*t)[33] = (float(*)[33])shbuf;
    for (int r = 0; r < 32; r += 8)
      t[ty + r][tx] = w[(by + ty + r) * ND + bx + tx];
    __syncthreads();
    for (int r = 0; r < 32; r += 8)
      o[(bx + ty + r) * ND + by + tx] = f2bf(t[tx][ty + r] * scale);
  } else if (blk < 8640) {
    int idx = (blk - 8448) * 256 + tid;
    if (idx >= 4095 * NH) return;
    int h = idx % NH;
    int di = idx / NH;
    int rel = di - 2047;          // rel = k - q
    int n = -rel;
    int ret = 0;
    if (n < 0) { ret = 16; n = -n; }
    int b;
    if (n < 8) {
      b = ret + n;
    } else {
      int v = (n >= 91) ? 7 : (n >= 64) ? 6 : (n >= 46) ? 5 : (n >= 32) ? 4
            : (n >= 23) ? 3 : (n >= 16) ? 2 : (n >= 12) ? 1 : 0;
      b = ret + 8 + v;
    }
    bias_tab[h * 4095 + di] = rel_emb[b * NH + h] * LOG2E;
  } else {
    int b = blk - 8640;
    int* red = (int*)shbuf;
    int acc = 1;
    for (int i = tid; i < NL; i += 256) {
      int m = mask[b * NL + i];
      maskadd[b * NL + i] = m ? 0.0f : -1e30f;
      acc &= (m != 0) ? 1 : 0;
    }
    red[tid] = acc;
    __syncthreads();
    for (int s2 = 128; s2 > 0; s2 >>= 1) {
      if (tid < s2) red[tid] &= red[tid + s2];
      __syncthreads();
    }
    if (tid == 0) maskall[b] = red[0];
  }
}

// ---- fused QKV GEMM, 128x96 tile: grid (32, 24) = 768 blocks = exactly 3/CU.
// y/8 = {Q,K,V}; nc0 = (y%8)*96. Wave-tile 64x48 (acc[4][3]). V blocks transpose
// through LDS for 256B-coalesced Vt stores.
__global__ __launch_bounds__(256) void k_gemm_qkv(const unsigned short* __restrict__ q_bf,
                                                  const unsigned short* __restrict__ kv_bf,
                                                  const unsigned short* __restrict__ Wt,
                                                  unsigned short* __restrict__ Qb,
                                                  unsigned short* __restrict__ Kb,
                                                  unsigned short* __restrict__ Vt) {
  __shared__ unsigned short S[14336];   // A: [0,8192) 16KB, B: [8192,14336) 12KB
  unsigned short* As = S;
  unsigned short* Bs = S + 8192;
  int tid = threadIdx.x;
  int wave = tid >> 6, lane = tid & 63;
  int lr = lane & 15, lg = lane >> 4;
  int m0 = blockIdx.x * 128;
  int z = blockIdx.y >> 3;                 // 0=Q, 1=K, 2=V
  int nc0 = (blockIdx.y & 7) * 96;         // col within the 768-wide section
  const unsigned short* A  = (z == 0) ? q_bf : kv_bf;
  const unsigned short* Bt = Wt + (size_t)blockIdx.y * 96 * ND;
  int wm = (wave >> 1) * 64, wn = (wave & 1) * 48;
  int srow = tid >> 3, spc = tid & 7;
  int sg = spc ^ (srow & 7);
  const unsigned short* Ag = A  + (size_t)(m0 + srow) * ND + sg * 8;
  const unsigned short* Bg = Bt + (size_t)srow * ND + sg * 8;
  f32x4 acc[4][3] = {};
  for (int t = 0; t < ND / 64; ++t) {
    int k0 = t * 64;
#pragma unroll
    for (int s = 0; s < 4; ++s)
      gl_lds16(Ag + (size_t)(s * 32) * ND + k0, &As[s * 2048 + tid * 8]);
#pragma unroll
    for (int s = 0; s < 3; ++s)
      gl_lds16(Bg + (size_t)(s * 32) * ND + k0, &Bs[s * 2048 + tid * 8]);
    __syncthreads();
#pragma unroll
    for (int ks = 0; ks < 2; ++ks) {
      bf16x8 af[4], bfr[3];
#pragma unroll
      for (int i = 0; i < 4; ++i) {
        int ar = wm + i * 16 + lr;
        af[i] = *(const bf16x8*)&As[ar * 64 + (((ks * 4 + lg) ^ (ar & 7)) * 8)];
      }
#pragma unroll
      for (int i = 0; i < 3; ++i) {
        int br = wn + i * 16 + lr;
        bfr[i] = *(const bf16x8*)&Bs[br * 64 + (((ks * 4 + lg) ^ (br & 7)) * 8)];
      }
#pragma unroll
      for (int mi = 0; mi < 4; ++mi)
#pragma unroll
        for (int ni = 0; ni < 3; ++ni)
          acc[mi][ni] = __builtin_amdgcn_mfma_f32_16x16x32_bf16(af[mi], bfr[ni], acc[mi][ni], 0, 0, 0);
    }
    __syncthreads();
  }
  if (z == 2) {
    // transpose through LDS: T[col][row], chunk-XOR swizzle (chunk ^= col&7)
    unsigned short* T = S;                 // 96*128 shorts = 24KB <= 28KB region
#pragma unroll
    for (int mi = 0; mi < 4; ++mi)
#pragma unroll
      for (int ni = 0; ni < 3; ++ni) {
        int col  = wn + ni * 16 + lr;      // dk within tile, 0..95
        int rowb = wm + mi * 16 + lg * 4;  // l within tile, 4 consecutive rows
        ushort4 v4;
        v4.x = f2bf(acc[mi][ni][0]);
        v4.y = f2bf(acc[mi][ni][1]);
        v4.z = f2bf(acc[mi][ni][2]);
        v4.w = f2bf(acc[mi][ni][3]);
        int addr = col * 128 + (((rowb >> 3) ^ (col & 7)) * 8) + (rowb & 7);
        *(ushort4*)&T[addr] = v4;          // 8B aligned: (rowb&7) in {0,4}
      }
    __syncthreads();
    int bb = m0 >> 11;
    unsigned short* vdst = Vt + (((size_t)bb * ND + nc0) << 11) + (m0 & 2047);
#pragma unroll
    for (int pass = 0; pass < 6; ++pass) {
      int col = (tid >> 4) + pass * 16;    // 16 cols per pass, 96 total
      int cc = tid & 15;                   // 16 chunks of 8 elems per col
      u32x4 val = *(const u32x4*)&T[col * 128 + ((cc ^ (col & 7)) * 8)];
      *(u32x4*)&vdst[((size_t)col << 11) + cc * 8] = val;  // 256B/16 lanes contiguous
    }
  } else {
#pragma unroll
    for (int mi = 0; mi < 4; ++mi)
#pragma unroll
      for (int ni = 0; ni < 3; ++ni)
#pragma unroll
        for (int r = 0; r < 4; ++r) {
          int row = m0 + wm + mi * 16 + lg * 4 + r;
          int col = nc0 + wn + ni * 16 + lr;
          unsigned short v = f2bf(acc[mi][ni][r]);
          if (z == 0) Qb[(size_t)row * ND + col] = v;
          else        Kb[(size_t)row * ND + col] = v;
        }
  }
}

// ---- out-proj GEMM: C[M,N] fp32 = A[M,K] bf16 * Bt[N,K]^T. 64x64 tile, BK=64,
// grid (64,12) = 768 blocks = exactly 3/CU (was 128x64, 384 = 1.5/CU imbalanced).
__global__ __launch_bounds__(256) void k_gemm(const unsigned short* __restrict__ A,
                                              const unsigned short* __restrict__ Bt,
                                              float* __restrict__ Cout,
                                              int Msz, int Nsz, int Ksz) {
  __shared__ unsigned short As[4096];   // [64][64]
  __shared__ unsigned short Bs[4096];
  int tid = threadIdx.x;
  int wave = tid >> 6, lane = tid & 63;
  int lr = lane & 15, lg = lane >> 4;
  int m0 = blockIdx.x * 64, n0 = blockIdx.y * 64;
  int wm = (wave >> 1) * 32, wn = (wave & 1) * 32;
  int srow = tid >> 3, spc = tid & 7;
  int sg = spc ^ (srow & 7);
  const unsigned short* Ag = A  + (size_t)(m0 + srow) * Ksz + sg * 8;
  const unsigned short* Bg = Bt + (size_t)(n0 + srow) * Ksz + sg * 8;
  f32x4 acc[2][2] = {};
  for (int t = 0; t < Ksz / 64; ++t) {
    int k0 = t * 64;
#pragma unroll
    for (int s = 0; s < 2; ++s) {
      gl_lds16(Ag + (size_t)(s * 32) * Ksz + k0, &As[s * 2048 + tid * 8]);
      gl_lds16(Bg + (size_t)(s * 32) * Ksz + k0, &Bs[s * 2048 + tid * 8]);
    }
    __syncthreads();
#pragma unroll
    for (int ks = 0; ks < 2; ++ks) {
      bf16x8 af[2], bfr[2];
#pragma unroll
      for (int i = 0; i < 2; ++i) {
        int ar = wm + i * 16 + lr;
        af[i] = *(const bf16x8*)&As[ar * 64 + (((ks * 4 + lg) ^ (ar & 7)) * 8)];
        int br = wn + i * 16 + lr;
        bfr[i] = *(const bf16x8*)&Bs[br * 64 + (((ks * 4 + lg) ^ (br & 7)) * 8)];
      }
#pragma unroll
      for (int mi = 0; mi < 2; ++mi)
#pragma unroll
        for (int ni = 0; ni < 2; ++ni)
          acc[mi][ni] = __builtin_amdgcn_mfma_f32_16x16x32_bf16(af[mi], bfr[ni], acc[mi][ni], 0, 0, 0);
    }
    __syncthreads();
  }
#pragma unroll
  for (int mi = 0; mi < 2; ++mi)
#pragma unroll
    for (int ni = 0; ni < 2; ++ni)
#pragma unroll
      for (int r = 0; r < 4; ++r) {
        int row = m0 + wm + mi * 16 + lg * 4 + r;
        int col = n0 + wn + ni * 16 + lr;
        Cout[(size_t)row * Nsz + col] = acc[mi][ni][r];
      }
}

// ---- fused flash attention (R14 structure) + XCD-aware block swizzle:
// flat grid 768; xcd = flat&7 gets 96 contiguous logical blocks = 3 heads ->
// each XCD's K/V working set is 1.5MB (L2-resident) instead of 12MB (thrash).
__global__ __launch_bounds__(256, 3) void k_attn(const unsigned short* __restrict__ Qb,
                                                 const unsigned short* __restrict__ Kb,
                                                 const unsigned short* __restrict__ Vt,
                                                 const float* __restrict__ bias_tab,
                                                 const float* __restrict__ maskadd,
                                                 const int* __restrict__ maskall,
                                                 unsigned short* __restrict__ Ob) {
  __shared__ unsigned short Ks[3][4096];   // [64 phys keys][64 dk], XOR-swizzled chunks
  __shared__ unsigned short Vs[3][4096];   // [64 dk][64 keys natural], XOR-swizzled
  __shared__ float biasw[384];             // near band: biasw[d+191]
  // XCD swizzle (bijective: 768 = 8 * 96)
  int flat = blockIdx.x;
  int nf = (flat & 7) * 96 + (flat >> 3);
  int qt = nf & 31, bh = nf >> 5;
  int b = bh / NH, h = bh % NH;
  int tid = threadIdx.x, wave = tid >> 6, lane = tid & 63;
  int lr = lane & 15, lg = lane >> 4;
  int q0 = qt * 64;
  for (int i = tid; i < 383; i += 256) biasw[i] = bias_tab[h * 4095 + 1856 + i];
  float cFlo = bias_tab[h * 4095];          // d <= -91 saturated (bucket 15)
  float cFhi = bias_tab[h * 4095 + 4094];   // d >= +91 saturated (bucket 31)
  const unsigned short* Kbase = Kb + (size_t)(b * NL) * ND + h * NDK;
  const unsigned short* Vbase = Vt + (size_t)(b * NH + h) * NDK * NL;
  int srow = tid >> 3, spc = tid & 7;
  int sg = spc ^ (srow & 7);
  // key permutation: phys row srow stores logical key l0; +32 phys -> l0+4
  int l0 = (srow >> 4) * 32 + ((srow >> 2) & 3) * 8 + (srow & 3);
  const unsigned short* Kg0 = Kbase + (size_t)l0 * ND + sg * 8;
  const unsigned short* Kg1 = Kbase + (size_t)(l0 + 4) * ND + sg * 8;
  const unsigned short* Vg0 = Vbase + (size_t)srow * NL + sg * 8;
  const unsigned short* Vg1 = Vbase + (size_t)(32 + srow) * NL + sg * 8;
  bf16x8 aq[2];
  int qw = q0 + wave * 16;
#pragma unroll
  for (int ks = 0; ks < 2; ++ks)
    aq[ks] = *(const bf16x8*)&Qb[(size_t)(b * NL + qw + lr) * ND + h * NDK + ks * 32 + lg * 8];
  const float* cbase = maskadd + b * NL;
  int nomask = __builtin_amdgcn_readfirstlane(maskall[b]);
  f32x4 accO[4] = {};
  float mst = -1e30f, lstl = 0.f;          // per-lane partial row-sum (16 keys/lane)
  int bconst = lg * 8 - wave * 16 - lr + 191 - q0;
  int src0 = (lane & 48) | ((lane >> 2) & 12);
  // prologue: stage tiles 0 and 1 into bufs 0, 1 (8 loads in flight)
  gl_lds16(Kg0, &Ks[0][tid * 8]);
  gl_lds16(Kg1, &Ks[0][2048 + tid * 8]);
  gl_lds16(Vg0, &Vs[0][tid * 8]);
  gl_lds16(Vg1, &Vs[0][2048 + tid * 8]);
  {
    size_t kok = (size_t)64 * ND, kov = 64;
    gl_lds16(Kg0 + kok, &Ks[1][tid * 8]);
    gl_lds16(Kg1 + kok, &Ks[1][2048 + tid * 8]);
    gl_lds16(Vg0 + kov, &Vs[1][tid * 8]);
    gl_lds16(Vg1 + kov, &Vs[1][2048 + tid * 8]);
  }
  asm volatile("s_waitcnt vmcnt(4) lgkmcnt(0)" ::: "memory");  // tile0 + biasw ready
  __builtin_amdgcn_s_barrier();
  // stage pointers for tile 2 onward (advance by constant stride per stage)
  const unsigned short* sk0 = Kg0 + (size_t)2 * 64 * ND;
  const unsigned short* sk1 = Kg1 + (size_t)2 * 64 * ND;
  const unsigned short* sv0 = Vg0 + 2 * 64;
  const unsigned short* sv1 = Vg1 + 2 * 64;

  auto body = [&](int kt_, auto CURc, auto PFc) {
    constexpr int CUR = decltype(CURc)::v;
    constexpr int PF  = decltype(PFc)::v;
    constexpr int ST  = (CUR + 2) % 3;
    float4 cv[2][2];
    if (!nomask) {
#pragma unroll
      for (int hf = 0; hf < 2; ++hf)
#pragma unroll
        for (int qd = 0; qd < 2; ++qd)
          cv[hf][qd] = *(const float4*)&cbase[kt_ * 64 + hf * 32 + lg * 8 + qd * 4];
    }
    if (PF) {
      gl_lds16(sk0, &Ks[ST][tid * 8]);
      gl_lds16(sk1, &Ks[ST][2048 + tid * 8]);
      gl_lds16(sv0, &Vs[ST][tid * 8]);
      gl_lds16(sv1, &Vs[ST][2048 + tid * 8]);
      sk0 += 64 * ND; sk1 += 64 * ND; sv0 += 64; sv1 += 64;
    }
    int kt64 = kt_ * 64;
    bool farlo = (kt64 + 63 < q0 - 90), farhi = (kt64 > q0 + 153);
    float ctile = farlo ? cFlo : (farhi ? cFhi : 0.0f);
    f32x4 s[4];
    __builtin_amdgcn_s_setprio(1);
    if (nomask && (farlo || farhi)) {
      const f32x4 z = {0.f, 0.f, 0.f, 0.f};
#pragma unroll
      for (int ni = 0; ni < 4; ++ni) {
        int kr = ni * 16 + lr;
        bf16x8 bk0 = *(const bf16x8*)&Ks[CUR][kr * 64 + ((lg ^ (lr & 7)) * 8)];
        bf16x8 bk1 = *(const bf16x8*)&Ks[CUR][kr * 64 + (((4 + lg) ^ (lr & 7)) * 8)];
        s[ni] = __builtin_amdgcn_mfma_f32_16x16x32_bf16(bk0, aq[0], z, 0, 0, 0);
        s[ni] = __builtin_amdgcn_mfma_f32_16x16x32_bf16(bk1, aq[1], s[ni], 0, 0, 0);
      }
    } else {
      if (farlo || farhi) {
#pragma unroll
        for (int ni = 0; ni < 4; ++ni)
#pragma unroll
          for (int r = 0; r < 4; ++r) s[ni][r] = 0.f;   // ctile folded later
      } else {
#pragma unroll
        for (int ni = 0; ni < 4; ++ni)
#pragma unroll
          for (int r = 0; r < 4; ++r)
            s[ni][r] = biasw[kt64 + (ni & 1) * 32 + (ni >> 1) * 4 + r + bconst];
      }
      if (!nomask) {
#pragma unroll
        for (int ni = 0; ni < 4; ++ni)
#pragma unroll
          for (int r = 0; r < 4; ++r)
            s[ni][r] += ((const float*)&cv[ni & 1][ni >> 1])[r];
      }
#pragma unroll
      for (int ni = 0; ni < 4; ++ni) {
        int kr = ni * 16 + lr;
        bf16x8 bk0 = *(const bf16x8*)&Ks[CUR][kr * 64 + ((lg ^ (lr & 7)) * 8)];
        bf16x8 bk1 = *(const bf16x8*)&Ks[CUR][kr * 64 + (((4 + lg) ^ (lr & 7)) * 8)];
        s[ni] = __builtin_amdgcn_mfma_f32_16x16x32_bf16(bk0, aq[0], s[ni], 0, 0, 0);
        s[ni] = __builtin_amdgcn_mfma_f32_16x16x32_bf16(bk1, aq[1], s[ni], 0, 0, 0);
      }
    }
    __builtin_amdgcn_s_setprio(0);
    // lane-local max over this lane's 16 keys (no cross-lane on common path)
    f32x4 t0, t1;
#pragma unroll
    for (int r = 0; r < 4; ++r) t0[r] = fmaxf(s[0][r], s[1][r]);
#pragma unroll
    for (int r = 0; r < 4; ++r) t1[r] = fmaxf(s[2][r], s[3][r]);
#pragma unroll
    for (int r = 0; r < 4; ++r) t0[r] = fmaxf(t0[r], t1[r]);
    float lm = fmaxf(fmaxf(t0[0], t0[1]), fmaxf(t0[2], t0[3]));
    if (!__all(lm + ctile - mst <= 8.0f)) {
      float pmax = fmaxf(lm, __shfl_xor(lm, 16));
      pmax = xmax32(pmax);
      float pm2 = pmax + ctile;
      float mnew = fmaxf(mst, pm2);
      float sc = fexp2(mst - mnew);
      float scB[4];
#pragma unroll
      for (int r = 0; r < 4; ++r) scB[r] = __shfl(sc, src0 | r);
#pragma unroll
      for (int ni = 0; ni < 4; ++ni)
#pragma unroll
        for (int r = 0; r < 4; ++r) accO[ni][r] *= scB[r];
      lstl *= sc;
      mst = mnew;
    }
    float msub = mst - ctile;
#pragma unroll
    for (int ni = 0; ni < 4; ++ni)
#pragma unroll
      for (int r = 0; r < 4; ++r) s[ni][r] = fexp2(s[ni][r] - msub);
    {
      f32x4 ta = s[0] + s[1];
      f32x4 tb = s[2] + s[3];
      ta = ta + tb;
      lstl += (ta[0] + ta[1]) + (ta[2] + ta[3]);
    }
    // pack P: lane's 16 values are exactly its PV A-fragments (key permutation)
    unsigned pw[8];
#pragma unroll
    for (int ni = 0; ni < 4; ++ni) {
      unsigned a, c;
      asm("v_cvt_pk_bf16_f32 %0, %1, %2" : "=v"(a) : "v"(s[ni][0]), "v"(s[ni][1]));
      asm("v_cvt_pk_bf16_f32 %0, %1, %2" : "=v"(c) : "v"(s[ni][2]), "v"(s[ni][3]));
      pw[ni * 2] = a; pw[ni * 2 + 1] = c;
    }
    u32x4 apw0 = {pw[0], pw[1], pw[4], pw[5]};
    u32x4 apw1 = {pw[2], pw[3], pw[6], pw[7]};
    bf16x8 ap0 = __builtin_bit_cast(bf16x8, apw0);
    bf16x8 ap1 = __builtin_bit_cast(bf16x8, apw1);
    // O += P @ V
    __builtin_amdgcn_s_setprio(1);
#pragma unroll
    for (int ni = 0; ni < 4; ++ni) {
      int vr = ni * 16 + lr;
      bf16x8 bv0 = *(const bf16x8*)&Vs[CUR][vr * 64 + ((lg ^ (lr & 7)) * 8)];
      bf16x8 bv1 = *(const bf16x8*)&Vs[CUR][vr * 64 + (((4 + lg) ^ (lr & 7)) * 8)];
      accO[ni] = __builtin_amdgcn_mfma_f32_16x16x32_bf16(ap0, bv0, accO[ni], 0, 0, 0);
      accO[ni] = __builtin_amdgcn_mfma_f32_16x16x32_bf16(ap1, bv1, accO[ni], 0, 0, 0);
    }
    __builtin_amdgcn_s_setprio(0);
    if (PF) asm volatile("s_waitcnt vmcnt(4)" ::: "memory");
    else    asm volatile("s_waitcnt vmcnt(0)" ::: "memory");
    __builtin_amdgcn_s_barrier();
  };

  for (int kt = 0; kt < 30; kt += 3) {   // tile kt uses buf kt%3; stages kt+2
    body(kt,     IC<0>{}, IC<1>{});
    body(kt + 1, IC<1>{}, IC<1>{});
    body(kt + 2, IC<2>{}, IC<1>{});
  }
  body(30, IC<0>{}, IC<0>{});
  body(31, IC<1>{}, IC<0>{});

  // epilogue: one cross-lane row-sum, then broadcast 1/l to accO's row layout
  float lst = lstl + __shfl_xor(lstl, 16);
  lst = xsum32(lst);
  float linv = 1.0f / lst;
  float lB[4];
#pragma unroll
  for (int r = 0; r < 4; ++r) lB[r] = __shfl(linv, src0 | r);
#pragma unroll
  for (int ni = 0; ni < 4; ++ni)
#pragma unroll
    for (int r = 0; r < 4; ++r) {
      int qg = qw + lg * 4 + r;
      int col = h * NDK + ni * 16 + lr;
      Ob[(size_t)(b * NL + qg) * ND + col] = f2bf(accO[ni][r] * lB[r]);
    }
}

extern "C" void kernel_launch(void* const* d_in, const int* in_sizes, int n_in,
                              void* d_out, int out_size, void* d_ws, size_t ws_size,
                              hipStream_t stream) {
  const float* query  = (const float*)d_in[0];
  const float* keyval = (const float*)d_in[1];
  const int*   mask   = (const int*)d_in[2];
  const float* Wq     = (const float*)d_in[3];
  const float* Wk     = (const float*)d_in[4];
  const float* Wv     = (const float*)d_in[5];
  const float* Wo     = (const float*)d_in[6];
  const float* rel    = (const float*)d_in[7];

  char* ws = (char*)d_ws;
  unsigned short* q_bf  = (unsigned short*)(ws);              // 4096x768 bf16
  unsigned short* kv_bf = (unsigned short*)(ws + 6291456);
  unsigned short* Wq_t  = (unsigned short*)(ws + 12582912);   // [N][K] bf16 (x 0.125*log2e)
  unsigned short* Wk_t  = (unsigned short*)(ws + 13762560);
  unsigned short* Wv_t  = (unsigned short*)(ws + 14942208);
  unsigned short* Wo_t  = (unsigned short*)(ws + 16121856);
  unsigned short* Qb    = (unsigned short*)(ws + 17301504);   // [B,L,H,DK]
  unsigned short* Kb    = (unsigned short*)(ws + 23592960);
  unsigned short* Vt    = (unsigned short*)(ws + 29884416);   // [B,768,L]
  unsigned short* Ob    = (unsigned short*)(ws + 36175872);   // [B,L,H*DK]
  float* bias_tab       = (float*)(ws + 42467328);            // [H][4095], x log2e
  float* maskadd        = (float*)(ws + 42663936);            // [B][L]
  int*   maskall        = (int*)(ws + 42680320);              // [B]

  k_prep<<<dim3(8642), dim3(256), 0, stream>>>(query, keyval, Wq, Wk, Wv, Wo, rel, mask,
                                               q_bf, kv_bf, Wq_t, Wk_t, Wv_t, Wo_t,
                                               bias_tab, maskadd, maskall);
  k_gemm_qkv<<<dim3(32, 24), dim3(256), 0, stream>>>(q_bf, kv_bf, Wq_t, Qb, Kb, Vt);
  k_attn<<<dim3(768), dim3(256), 0, stream>>>(Qb, Kb, Vt, bias_tab, maskadd, maskall, Ob);
  k_gemm<<<dim3(64, 12), dim3(256), 0, stream>>>(Ob, Wo_t, (float*)d_out, NM, ND, ND);
}

// Round 16
// 93.180 us; speedup vs baseline: 1.2609x; 1.0014x over previous
//
#include <hip/hip_runtime.h>
#include <stdint.h>

typedef __attribute__((ext_vector_type(8))) short bf16x8;
typedef __attribute__((ext_vector_type(4))) float f32x4;
typedef __attribute__((ext_vector_type(4))) unsigned int u32x4;

#define NB 2
#define NL 2048
#define ND 768
#define NH 12
#define NDK 64
#define NM 4096   // NB*NL
#define LOG2E 1.4426950408889634f

template<int N> struct IC { static constexpr int v = N; };

__device__ __forceinline__ unsigned short f2bf(float f) {
  unsigned u = __builtin_bit_cast(unsigned, f);
  u += 0x7FFFu + ((u >> 16) & 1u);          // RNE
  return (unsigned short)(u >> 16);
}

__device__ __forceinline__ float fexp2(float x) {
  float r;
  asm("v_exp_f32 %0, %1" : "=v"(r) : "v"(x));
  return r;
}

__device__ __forceinline__ float xmax32(float x) { return fmaxf(x, __shfl_xor(x, 32)); }
__device__ __forceinline__ float xsum32(float x) { return x + __shfl_xor(x, 32); }

__device__ __forceinline__ void gl_lds16(const unsigned short* g, unsigned short* l) {
  __builtin_amdgcn_global_load_lds((const __attribute__((address_space(1))) void*)g,
                                   (__attribute__((address_space(3))) void*)l, 16, 0, 0);
}

// ---- merged prep: conv (0..6143) | wt (6144..8447) | bias (8448..8639) | maskadd (8640..8641)
__global__ __launch_bounds__(256) void k_prep(const float* __restrict__ query,
                                              const float* __restrict__ keyval,
                                              const float* __restrict__ Wq,
                                              const float* __restrict__ Wk,
                                              const float* __restrict__ Wv,
                                              const float* __restrict__ Wo,
                                              const float* __restrict__ rel_emb,
                                              const int* __restrict__ mask,
                                              unsigned short* __restrict__ q_bf,
                                              unsigned short* __restrict__ kv_bf,
                                              unsigned short* __restrict__ Wq_t,
                                              unsigned short* __restrict__ Wk_t,
                                              unsigned short* __restrict__ Wv_t,
                                              unsigned short* __restrict__ Wo_t,
                                              float* __restrict__ bias_tab,
                                              float* __restrict__ maskadd,
                                              int* __restrict__ maskall) {
  __shared__ float shbuf[32 * 33];
  int blk = blockIdx.x, tid = threadIdx.x;
  if (blk < 6144) {
    int y = blk / 3072;
    int i = (blk - y * 3072) * 256 + tid;
    const float* src = y ? keyval : query;
    unsigned short* dst = y ? kv_bf : q_bf;
    float4 v = ((const float4*)src)[i];
    ushort4 o;
    o.x = f2bf(v.x); o.y = f2bf(v.y); o.z = f2bf(v.z); o.w = f2bf(v.w);
    ((ushort4*)dst)[i] = o;
  } else if (blk < 8448) {
    int rel = blk - 6144;
    int z = rel / 576, r2 = rel - z * 576;
    int bx = (r2 % 24) * 32, by = (r2 / 24) * 32;
    const float* w = (z == 0) ? Wq : (z == 1) ? Wk : (z == 2) ? Wv : Wo;
    unsigned short* o = (z == 0) ? Wq_t : (z == 1) ? Wk_t : (z == 2) ? Wv_t : Wo_t;
    float scale = (z == 0) ? 0.125f * LOG2E : 1.0f;
    int tx = tid & 31, ty = tid >> 5;
    float (*t)[33] = (float(*)[33])shbuf;
    for (int r = 0; r < 32; r += 8)
      t[ty + r][tx] = w[(by + ty + r) * ND + bx + tx];
    __syncthreads();
    for (int r = 0; r < 32; r += 8)
      o[(bx + ty + r) * ND + by + tx] = f2bf(t[tx][ty + r] * scale);
  } else if (blk < 8640) {
    int idx = (blk - 8448) * 256 + tid;
    if (idx >= 4095 * NH) return;
    int h = idx % NH;
    int di = idx / NH;
    int rel = di - 2047;          // rel = k - q
    int n = -rel;
    int ret = 0;
    if (n < 0) { ret = 16; n = -n; }
    int b;
    if (n < 8) {
      b = ret + n;
    } else {
      int v = (n >= 91) ? 7 : (n >= 64) ? 6 : (n >= 46) ? 5 : (n >= 32) ? 4
            : (n >= 23) ? 3 : (n >= 16) ? 2 : (n >= 12) ? 1 : 0;
      b = ret + 8 + v;
    }
    bias_tab[h * 4095 + di] = rel_emb[b * NH + h] * LOG2E;
  } else {
    int b = blk - 8640;
    int* red = (int*)shbuf;
    int acc = 1;
    for (int i = tid; i < NL; i += 256) {
      int m = mask[b * NL + i];
      maskadd[b * NL + i] = m ? 0.0f : -1e30f;
      acc &= (m != 0) ? 1 : 0;
    }
    red[tid] = acc;
    __syncthreads();
    for (int s2 = 128; s2 > 0; s2 >>= 1) {
      if (tid < s2) red[tid] &= red[tid + s2];
      __syncthreads();
    }
    if (tid == 0) maskall[b] = red[0];
  }
}

// ---- fused QKV GEMM, 128x96 tile, flat grid 768 with XCD swizzle (y-fastest
// logical order): each XCD's 96 blocks = 4 A-panels x 24 weight-columns -> A-panel
// stays L2-resident across its 24 consecutive blocks (cuts ~300MB of L3 re-reads).
__global__ __launch_bounds__(256) void k_gemm_qkv(const unsigned short* __restrict__ q_bf,
                                                  const unsigned short* __restrict__ kv_bf,
                                                  const unsigned short* __restrict__ Wt,
                                                  unsigned short* __restrict__ Qb,
                                                  unsigned short* __restrict__ Kb,
                                                  unsigned short* __restrict__ Vt) {
  __shared__ unsigned short S[14336];   // A: [0,8192) 16KB, B: [8192,14336) 12KB
  unsigned short* As = S;
  unsigned short* Bs = S + 8192;
  int flat = blockIdx.x;
  int nf = (flat & 7) * 96 + (flat >> 3);   // bijective: 768 = 8*96
  int px = nf / 24;                          // A-panel index (0..31), 24 consec nf share it
  int y  = nf - px * 24;                     // weight column (0..23)
  int tid = threadIdx.x;
  int wave = tid >> 6, lane = tid & 63;
  int lr = lane & 15, lg = lane >> 4;
  int m0 = px * 128;
  int z = y >> 3;                  // 0=Q, 1=K, 2=V
  int nc0 = (y & 7) * 96;          // col within the 768-wide section
  const unsigned short* A  = (z == 0) ? q_bf : kv_bf;
  const unsigned short* Bt = Wt + (size_t)y * 96 * ND;
  int wm = (wave >> 1) * 64, wn = (wave & 1) * 48;
  int srow = tid >> 3, spc = tid & 7;
  int sg = spc ^ (srow & 7);
  const unsigned short* Ag = A  + (size_t)(m0 + srow) * ND + sg * 8;
  const unsigned short* Bg = Bt + (size_t)srow * ND + sg * 8;
  f32x4 acc[4][3] = {};
  for (int t = 0; t < ND / 64; ++t) {
    int k0 = t * 64;
#pragma unroll
    for (int s = 0; s < 4; ++s)
      gl_lds16(Ag + (size_t)(s * 32) * ND + k0, &As[s * 2048 + tid * 8]);
#pragma unroll
    for (int s = 0; s < 3; ++s)
      gl_lds16(Bg + (size_t)(s * 32) * ND + k0, &Bs[s * 2048 + tid * 8]);
    __syncthreads();
#pragma unroll
    for (int ks = 0; ks < 2; ++ks) {
      bf16x8 af[4], bfr[3];
#pragma unroll
      for (int i = 0; i < 4; ++i) {
        int ar = wm + i * 16 + lr;
        af[i] = *(const bf16x8*)&As[ar * 64 + (((ks * 4 + lg) ^ (ar & 7)) * 8)];
      }
#pragma unroll
      for (int i = 0; i < 3; ++i) {
        int br = wn + i * 16 + lr;
        bfr[i] = *(const bf16x8*)&Bs[br * 64 + (((ks * 4 + lg) ^ (br & 7)) * 8)];
      }
#pragma unroll
      for (int mi = 0; mi < 4; ++mi)
#pragma unroll
        for (int ni = 0; ni < 3; ++ni)
          acc[mi][ni] = __builtin_amdgcn_mfma_f32_16x16x32_bf16(af[mi], bfr[ni], acc[mi][ni], 0, 0, 0);
    }
    __syncthreads();
  }
  if (z == 2) {
    // transpose through LDS: T[col][row], chunk-XOR swizzle (chunk ^= col&7)
    unsigned short* T = S;                 // 96*128 shorts = 24KB <= 28KB region
#pragma unroll
    for (int mi = 0; mi < 4; ++mi)
#pragma unroll
      for (int ni = 0; ni < 3; ++ni) {
        int col  = wn + ni * 16 + lr;      // dk within tile, 0..95
        int rowb = wm + mi * 16 + lg * 4;  // l within tile, 4 consecutive rows
        ushort4 v4;
        v4.x = f2bf(acc[mi][ni][0]);
        v4.y = f2bf(acc[mi][ni][1]);
        v4.z = f2bf(acc[mi][ni][2]);
        v4.w = f2bf(acc[mi][ni][3]);
        int addr = col * 128 + (((rowb >> 3) ^ (col & 7)) * 8) + (rowb & 7);
        *(ushort4*)&T[addr] = v4;          // 8B aligned: (rowb&7) in {0,4}
      }
    __syncthreads();
    int bb = m0 >> 11;
    unsigned short* vdst = Vt + (((size_t)bb * ND + nc0) << 11) + (m0 & 2047);
#pragma unroll
    for (int pass = 0; pass < 6; ++pass) {
      int col = (tid >> 4) + pass * 16;    // 16 cols per pass, 96 total
      int cc = tid & 15;                   // 16 chunks of 8 elems per col
      u32x4 val = *(const u32x4*)&T[col * 128 + ((cc ^ (col & 7)) * 8)];
      *(u32x4*)&vdst[((size_t)col << 11) + cc * 8] = val;  // 256B/16 lanes contiguous
    }
  } else {
#pragma unroll
    for (int mi = 0; mi < 4; ++mi)
#pragma unroll
      for (int ni = 0; ni < 3; ++ni)
#pragma unroll
        for (int r = 0; r < 4; ++r) {
          int row = m0 + wm + mi * 16 + lg * 4 + r;
          int col = nc0 + wn + ni * 16 + lr;
          unsigned short v = f2bf(acc[mi][ni][r]);
          if (z == 0) Qb[(size_t)row * ND + col] = v;
          else        Kb[(size_t)row * ND + col] = v;
        }
  }
}

// ---- out-proj GEMM: C[M,N] fp32 = A[M,K] bf16 * Bt[N,K]^T. 64x64 tile, flat grid
// 768 + XCD swizzle (y-fastest: A-panel L2-resident across its 12 blocks) + dbuf
// LDS with prefetch-before-compute (stage latency overlaps the MFMA cluster).
__global__ __launch_bounds__(256) void k_gemm(const unsigned short* __restrict__ A,
                                              const unsigned short* __restrict__ Bt,
                                              float* __restrict__ Cout,
                                              int Msz, int Nsz, int Ksz) {
  __shared__ unsigned short As[2][4096];   // [64][64] per buf
  __shared__ unsigned short Bs[2][4096];
  int flat = blockIdx.x;
  int nf = (flat & 7) * 96 + (flat >> 3);   // bijective: 768 = 8*96
  int px = nf / 12;                          // A-panel (0..63), 12 consec nf share it
  int y  = nf - px * 12;                     // N-column (0..11)
  int tid = threadIdx.x;
  int wave = tid >> 6, lane = tid & 63;
  int lr = lane & 15, lg = lane >> 4;
  int m0 = px * 64, n0 = y * 64;
  int wm = (wave >> 1) * 32, wn = (wave & 1) * 32;
  int srow = tid >> 3, spc = tid & 7;
  int sg = spc ^ (srow & 7);
  const unsigned short* Ag = A  + (size_t)(m0 + srow) * Ksz + sg * 8;
  const unsigned short* Bg = Bt + (size_t)(n0 + srow) * Ksz + sg * 8;
  f32x4 acc[2][2] = {};
  const int KT = Ksz >> 6;
  // prologue: stage tile 0 into buf 0
#pragma unroll
  for (int s = 0; s < 2; ++s) {
    gl_lds16(Ag + (size_t)(s * 32) * Ksz, &As[0][s * 2048 + tid * 8]);
    gl_lds16(Bg + (size_t)(s * 32) * Ksz, &Bs[0][s * 2048 + tid * 8]);
  }
  __syncthreads();
  int cur = 0;
  for (int t = 0; t < KT; ++t) {
    if (t + 1 < KT) {              // prefetch next tile; overlaps compute below
      int k0 = (t + 1) << 6;
#pragma unroll
      for (int s = 0; s < 2; ++s) {
        gl_lds16(Ag + (size_t)(s * 32) * Ksz + k0, &As[cur ^ 1][s * 2048 + tid * 8]);
        gl_lds16(Bg + (size_t)(s * 32) * Ksz + k0, &Bs[cur ^ 1][s * 2048 + tid * 8]);
      }
    }
#pragma unroll
    for (int ks = 0; ks < 2; ++ks) {
      bf16x8 af[2], bfr[2];
#pragma unroll
      for (int i = 0; i < 2; ++i) {
        int ar = wm + i * 16 + lr;
        af[i] = *(const bf16x8*)&As[cur][ar * 64 + (((ks * 4 + lg) ^ (ar & 7)) * 8)];
        int br = wn + i * 16 + lr;
        bfr[i] = *(const bf16x8*)&Bs[cur][br * 64 + (((ks * 4 + lg) ^ (br & 7)) * 8)];
      }
#pragma unroll
      for (int mi = 0; mi < 2; ++mi)
#pragma unroll
        for (int ni = 0; ni < 2; ++ni)
          acc[mi][ni] = __builtin_amdgcn_mfma_f32_16x16x32_bf16(af[mi], bfr[ni], acc[mi][ni], 0, 0, 0);
    }
    __syncthreads();               // drains prefetch + protects buffer swap
    cur ^= 1;
  }
#pragma unroll
  for (int mi = 0; mi < 2; ++mi)
#pragma unroll
    for (int ni = 0; ni < 2; ++ni)
#pragma unroll
      for (int r = 0; r < 4; ++r) {
        int row = m0 + wm + mi * 16 + lg * 4 + r;
        int col = n0 + wn + ni * 16 + lr;
        Cout[(size_t)row * Nsz + col] = acc[mi][ni][r];
      }
}

// ---- fused flash attention (R15 structure, unchanged): swapped-QK^T (exp2),
// 3-buffer counted-vmcnt pipeline, far-tile zero-C bias, lane-local softmax,
// XCD-aware block swizzle (FETCH 52->9 MB verified).
__global__ __launch_bounds__(256, 3) void k_attn(const unsigned short* __restrict__ Qb,
                                                 const unsigned short* __restrict__ Kb,
                                                 const unsigned short* __restrict__ Vt,
                                                 const float* __restrict__ bias_tab,
                                                 const float* __restrict__ maskadd,
                                                 const int* __restrict__ maskall,
                                                 unsigned short* __restrict__ Ob) {
  __shared__ unsigned short Ks[3][4096];   // [64 phys keys][64 dk], XOR-swizzled chunks
  __shared__ unsigned short Vs[3][4096];   // [64 dk][64 keys natural], XOR-swizzled
  __shared__ float biasw[384];             // near band: biasw[d+191]
  int flat = blockIdx.x;
  int nf = (flat & 7) * 96 + (flat >> 3);
  int qt = nf & 31, bh = nf >> 5;
  int b = bh / NH, h = bh % NH;
  int tid = threadIdx.x, wave = tid >> 6, lane = tid & 63;
  int lr = lane & 15, lg = lane >> 4;
  int q0 = qt * 64;
  for (int i = tid; i < 383; i += 256) biasw[i] = bias_tab[h * 4095 + 1856 + i];
  float cFlo = bias_tab[h * 4095];          // d <= -91 saturated (bucket 15)
  float cFhi = bias_tab[h * 4095 + 4094];   // d >= +91 saturated (bucket 31)
  const unsigned short* Kbase = Kb + (size_t)(b * NL) * ND + h * NDK;
  const unsigned short* Vbase = Vt + (size_t)(b * NH + h) * NDK * NL;
  int srow = tid >> 3, spc = tid & 7;
  int sg = spc ^ (srow & 7);
  // key permutation: phys row srow stores logical key l0; +32 phys -> l0+4
  int l0 = (srow >> 4) * 32 + ((srow >> 2) & 3) * 8 + (srow & 3);
  const unsigned short* Kg0 = Kbase + (size_t)l0 * ND + sg * 8;
  const unsigned short* Kg1 = Kbase + (size_t)(l0 + 4) * ND + sg * 8;
  const unsigned short* Vg0 = Vbase + (size_t)srow * NL + sg * 8;
  const unsigned short* Vg1 = Vbase + (size_t)(32 + srow) * NL + sg * 8;
  bf16x8 aq[2];
  int qw = q0 + wave * 16;
#pragma unroll
  for (int ks = 0; ks < 2; ++ks)
    aq[ks] = *(const bf16x8*)&Qb[(size_t)(b * NL + qw + lr) * ND + h * NDK + ks * 32 + lg * 8];
  const float* cbase = maskadd + b * NL;
  int nomask = __builtin_amdgcn_readfirstlane(maskall[b]);
  f32x4 accO[4] = {};
  float mst = -1e30f, lstl = 0.f;          // per-lane partial row-sum (16 keys/lane)
  int bconst = lg * 8 - wave * 16 - lr + 191 - q0;
  int src0 = (lane & 48) | ((lane >> 2) & 12);
  // prologue: stage tiles 0 and 1 into bufs 0, 1 (8 loads in flight)
  gl_lds16(Kg0, &Ks[0][tid * 8]);
  gl_lds16(Kg1, &Ks[0][2048 + tid * 8]);
  gl_lds16(Vg0, &Vs[0][tid * 8]);
  gl_lds16(Vg1, &Vs[0][2048 + tid * 8]);
  {
    size_t kok = (size_t)64 * ND, kov = 64;
    gl_lds16(Kg0 + kok, &Ks[1][tid * 8]);
    gl_lds16(Kg1 + kok, &Ks[1][2048 + tid * 8]);
    gl_lds16(Vg0 + kov, &Vs[1][tid * 8]);
    gl_lds16(Vg1 + kov, &Vs[1][2048 + tid * 8]);
  }
  asm volatile("s_waitcnt vmcnt(4) lgkmcnt(0)" ::: "memory");  // tile0 + biasw ready
  __builtin_amdgcn_s_barrier();
  // stage pointers for tile 2 onward (advance by constant stride per stage)
  const unsigned short* sk0 = Kg0 + (size_t)2 * 64 * ND;
  const unsigned short* sk1 = Kg1 + (size_t)2 * 64 * ND;
  const unsigned short* sv0 = Vg0 + 2 * 64;
  const unsigned short* sv1 = Vg1 + 2 * 64;

  auto body = [&](int kt_, auto CURc, auto PFc) {
    constexpr int CUR = decltype(CURc)::v;
    constexpr int PF  = decltype(PFc)::v;
    constexpr int ST  = (CUR + 2) % 3;
    float4 cv[2][2];
    if (!nomask) {
#pragma unroll
      for (int hf = 0; hf < 2; ++hf)
#pragma unroll
        for (int qd = 0; qd < 2; ++qd)
          cv[hf][qd] = *(const float4*)&cbase[kt_ * 64 + hf * 32 + lg * 8 + qd * 4];
    }
    if (PF) {
      gl_lds16(sk0, &Ks[ST][tid * 8]);
      gl_lds16(sk1, &Ks[ST][2048 + tid * 8]);
      gl_lds16(sv0, &Vs[ST][tid * 8]);
      gl_lds16(sv1, &Vs[ST][2048 + tid * 8]);
      sk0 += 64 * ND; sk1 += 64 * ND; sv0 += 64; sv1 += 64;
    }
    int kt64 = kt_ * 64;
    bool farlo = (kt64 + 63 < q0 - 90), farhi = (kt64 > q0 + 153);
    float ctile = farlo ? cFlo : (farhi ? cFhi : 0.0f);
    f32x4 s[4];
    __builtin_amdgcn_s_setprio(1);
    if (nomask && (farlo || farhi)) {
      const f32x4 z = {0.f, 0.f, 0.f, 0.f};
#pragma unroll
      for (int ni = 0; ni < 4; ++ni) {
        int kr = ni * 16 + lr;
        bf16x8 bk0 = *(const bf16x8*)&Ks[CUR][kr * 64 + ((lg ^ (lr & 7)) * 8)];
        bf16x8 bk1 = *(const bf16x8*)&Ks[CUR][kr * 64 + (((4 + lg) ^ (lr & 7)) * 8)];
        s[ni] = __builtin_amdgcn_mfma_f32_16x16x32_bf16(bk0, aq[0], z, 0, 0, 0);
        s[ni] = __builtin_amdgcn_mfma_f32_16x16x32_bf16(bk1, aq[1], s[ni], 0, 0, 0);
      }
    } else {
      if (farlo || farhi) {
#pragma unroll
        for (int ni = 0; ni < 4; ++ni)
#pragma unroll
          for (int r = 0; r < 4; ++r) s[ni][r] = 0.f;   // ctile folded later
      } else {
#pragma unroll
        for (int ni = 0; ni < 4; ++ni)
#pragma unroll
          for (int r = 0; r < 4; ++r)
            s[ni][r] = biasw[kt64 + (ni & 1) * 32 + (ni >> 1) * 4 + r + bconst];
      }
      if (!nomask) {
#pragma unroll
        for (int ni = 0; ni < 4; ++ni)
#pragma unroll
          for (int r = 0; r < 4; ++r)
            s[ni][r] += ((const float*)&cv[ni & 1][ni >> 1])[r];
      }
#pragma unroll
      for (int ni = 0; ni < 4; ++ni) {
        int kr = ni * 16 + lr;
        bf16x8 bk0 = *(const bf16x8*)&Ks[CUR][kr * 64 + ((lg ^ (lr & 7)) * 8)];
        bf16x8 bk1 = *(const bf16x8*)&Ks[CUR][kr * 64 + (((4 + lg) ^ (lr & 7)) * 8)];
        s[ni] = __builtin_amdgcn_mfma_f32_16x16x32_bf16(bk0, aq[0], s[ni], 0, 0, 0);
        s[ni] = __builtin_amdgcn_mfma_f32_16x16x32_bf16(bk1, aq[1], s[ni], 0, 0, 0);
      }
    }
    __builtin_amdgcn_s_setprio(0);
    // lane-local max over this lane's 16 keys (no cross-lane on common path)
    f32x4 t0, t1;
#pragma unroll
    for (int r = 0; r < 4; ++r) t0[r] = fmaxf(s[0][r], s[1][r]);
#pragma unroll
    for (int r = 0; r < 4; ++r) t1[r] = fmaxf(s[2][r], s[3][r]);
#pragma unroll
    for (int r = 0; r < 4; ++r) t0[r] = fmaxf(t0[r], t1[r]);
    float lm = fmaxf(fmaxf(t0[0], t0[1]), fmaxf(t0[2], t0[3]));
    if (!__all(lm + ctile - mst <= 8.0f)) {
      float pmax = fmaxf(lm, __shfl_xor(lm, 16));
      pmax = xmax32(pmax);
      float pm2 = pmax + ctile;
      float mnew = fmaxf(mst, pm2);
      float sc = fexp2(mst - mnew);
      float scB[4];
#pragma unroll
      for (int r = 0; r < 4; ++r) scB[r] = __shfl(sc, src0 | r);
#pragma unroll
      for (int ni = 0; ni < 4; ++ni)
#pragma unroll
        for (int r = 0; r < 4; ++r) accO[ni][r] *= scB[r];
      lstl *= sc;
      mst = mnew;
    }
    float msub = mst - ctile;
#pragma unroll
    for (int ni = 0; ni < 4; ++ni)
#pragma unroll
      for (int r = 0; r < 4; ++r) s[ni][r] = fexp2(s[ni][r] - msub);
    {
      f32x4 ta = s[0] + s[1];
      f32x4 tb = s[2] + s[3];
      ta = ta + tb;
      lstl += (ta[0] + ta[1]) + (ta[2] + ta[3]);
    }
    // pack P: lane's 16 values are exactly its PV A-fragments (key permutation)
    unsigned pw[8];
#pragma unroll
    for (int ni = 0; ni < 4; ++ni) {
      unsigned a, c;
      asm("v_cvt_pk_bf16_f32 %0, %1, %2" : "=v"(a) : "v"(s[ni][0]), "v"(s[ni][1]));
      asm("v_cvt_pk_bf16_f32 %0, %1, %2" : "=v"(c) : "v"(s[ni][2]), "v"(s[ni][3]));
      pw[ni * 2] = a; pw[ni * 2 + 1] = c;
    }
    u32x4 apw0 = {pw[0], pw[1], pw[4], pw[5]};
    u32x4 apw1 = {pw[2], pw[3], pw[6], pw[7]};
    bf16x8 ap0 = __builtin_bit_cast(bf16x8, apw0);
    bf16x8 ap1 = __builtin_bit_cast(bf16x8, apw1);
    // O += P @ V
    __builtin_amdgcn_s_setprio(1);
#pragma unroll
    for (int ni = 0; ni < 4; ++ni) {
      int vr = ni * 16 + lr;
      bf16x8 bv0 = *(const bf16x8*)&Vs[CUR][vr * 64 + ((lg ^ (lr & 7)) * 8)];
      bf16x8 bv1 = *(const bf16x8*)&Vs[CUR][vr * 64 + (((4 + lg) ^ (lr & 7)) * 8)];
      accO[ni] = __builtin_amdgcn_mfma_f32_16x16x32_bf16(ap0, bv0, accO[ni], 0, 0, 0);
      accO[ni] = __builtin_amdgcn_mfma_f32_16x16x32_bf16(ap1, bv1, accO[ni], 0, 0, 0);
    }
    __builtin_amdgcn_s_setprio(0);
    if (PF) asm volatile("s_waitcnt vmcnt(4)" ::: "memory");
    else    asm volatile("s_waitcnt vmcnt(0)" ::: "memory");
    __builtin_amdgcn_s_barrier();
  };

  for (int kt = 0; kt < 30; kt += 3) {   // tile kt uses buf kt%3; stages kt+2
    body(kt,     IC<0>{}, IC<1>{});
    body(kt + 1, IC<1>{}, IC<1>{});
    body(kt + 2, IC<2>{}, IC<1>{});
  }
  body(30, IC<0>{}, IC<0>{});
  body(31, IC<1>{}, IC<0>{});

  // epilogue: one cross-lane row-sum, then broadcast 1/l to accO's row layout
  float lst = lstl + __shfl_xor(lstl, 16);
  lst = xsum32(lst);
  float linv = 1.0f / lst;
  float lB[4];
#pragma unroll
  for (int r = 0; r < 4; ++r) lB[r] = __shfl(linv, src0 | r);
#pragma unroll
  for (int ni = 0; ni < 4; ++ni)
#pragma unroll
    for (int r = 0; r < 4; ++r) {
      int qg = qw + lg * 4 + r;
      int col = h * NDK + ni * 16 + lr;
      Ob[(size_t)(b * NL + qg) * ND + col] = f2bf(accO[ni][r] * lB[r]);
    }
}

extern "C" void kernel_launch(void* const* d_in, const int* in_sizes, int n_in,
                              void* d_out, int out_size, void* d_ws, size_t ws_size,
                              hipStream_t stream) {
  const float* query  = (const float*)d_in[0];
  const float* keyval = (const float*)d_in[1];
  const int*   mask   = (const int*)d_in[2];
  const float* Wq     = (const float*)d_in[3];
  const float* Wk     = (const float*)d_in[4];
  const float* Wv     = (const float*)d_in[5];
  const float* Wo     = (const float*)d_in[6];
  const float* rel    = (const float*)d_in[7];

  char* ws = (char*)d_ws;
  unsigned short* q_bf  = (unsigned short*)(ws);              // 4096x768 bf16
  unsigned short* kv_bf = (unsigned short*)(ws + 6291456);
  unsigned short* Wq_t  = (unsigned short*)(ws + 12582912);   // [N][K] bf16 (x 0.125*log2e)
  unsigned short* Wk_t  = (unsigned short*)(ws + 13762560);
  unsigned short* Wv_t  = (unsigned short*)(ws + 14942208);
  unsigned short* Wo_t  = (unsigned short*)(ws + 16121856);
  unsigned short* Qb    = (unsigned short*)(ws + 17301504);   // [B,L,H,DK]
  unsigned short* Kb    = (unsigned short*)(ws + 23592960);
  unsigned short* Vt    = (unsigned short*)(ws + 29884416);   // [B,768,L]
  unsigned short* Ob    = (unsigned short*)(ws + 36175872);   // [B,L,H*DK]
  float* bias_tab       = (float*)(ws + 42467328);            // [H][4095], x log2e
  float* maskadd        = (float*)(ws + 42663936);            // [B][L]
  int*   maskall        = (int*)(ws + 42680320);              // [B]

  k_prep<<<dim3(8642), dim3(256), 0, stream>>>(query, keyval, Wq, Wk, Wv, Wo, rel, mask,
                                               q_bf, kv_bf, Wq_t, Wk_t, Wv_t, Wo_t,
                                               bias_tab, maskadd, maskall);
  k_gemm_qkv<<<dim3(768), dim3(256), 0, stream>>>(q_bf, kv_bf, Wq_t, Qb, Kb, Vt);
  k_attn<<<dim3(768), dim3(256), 0, stream>>>(Qb, Kb, Vt, bias_tab, maskadd, maskall, Ob);
  k_gemm<<<dim3(768), dim3(256), 0, stream>>>(Ob, Wo_t, (float*)d_out, NM, ND, ND);
}